// Round 17
// baseline (285.131 us; speedup 1.0000x reference)
//
#include <hip/hip_runtime.h>
#include <hip/hip_bf16.h>
#include <cstdint>
#include <cstddef>

// ---- problem constants ----
#define B_N       4
#define C_INCH    23
#define T_N       8
#define W_IMG     128
#define L_SEQ     8192
#define BLROWS    32768      // B_N * L_SEQ
#define DM_       256
#define D_INNER_  512
#define CONV_DIM_ 544
#define D_PROJ    1064
#define KPATCH    368        // C_INCH*4*4
#define QCH       64         // scan chunk length
#define NCH       128        // chunks per batch
#define RECW      56         // packed scan record (floats): B16 C16 dA8 dt8 ldA8

typedef unsigned short ushort_t;
typedef unsigned int uint_t;
typedef __attribute__((ext_vector_type(8))) short short8;
typedef __attribute__((ext_vector_type(4))) float f32x4;

__device__ __forceinline__ float b2f(ushort_t u) {
    union { float f; uint_t u; } v; v.u = ((uint_t)u) << 16; return v.f;
}
__device__ __forceinline__ ushort_t f2b(float f) {
    union { float f; uint_t u; } v; v.f = f;
    uint_t r = v.u + 0x7fffu + ((v.u >> 16) & 1u);
    return (ushort_t)(r >> 16);
}

// async global->LDS, 16B per lane. LDS dest = wave-uniform base + lane*16.
__device__ __forceinline__ void gload_lds16(const ushort_t* g, ushort_t* l) {
    __builtin_amdgcn_global_load_lds(
        (const __attribute__((address_space(1))) unsigned int*)g,
        (__attribute__((address_space(3))) unsigned int*)l, 16, 0, 0);
}

// build a bf16 short8 frag from 8 consecutive f32 (or zeros if !live)
__device__ __forceinline__ short8 frag8(const float* q, bool live) {
    short8 f;
    if (live) {
        float4 lo = *(const float4*)q, hi = *(const float4*)(q + 4);
        f[0] = (short)f2b(lo.x); f[1] = (short)f2b(lo.y);
        f[2] = (short)f2b(lo.z); f[3] = (short)f2b(lo.w);
        f[4] = (short)f2b(hi.x); f[5] = (short)f2b(hi.y);
        f[6] = (short)f2b(hi.z); f[7] = (short)f2b(hi.w);
    } else {
        #pragma unroll
        for (int e = 0; e < 8; ++e) f[e] = 0;
    }
    return f;
}

// gate one packed pair: out = pack(bf16(y0*z0), bf16(y1*z1))
__device__ __forceinline__ uint_t gate2(uint_t yw, uint_t zw) {
    float y0 = b2f((ushort_t)(yw & 0xffffu)), y1 = b2f((ushort_t)(yw >> 16));
    float z0 = b2f((ushort_t)(zw & 0xffffu)), z1 = b2f((ushort_t)(zw >> 16));
    return (uint_t)f2b(y0 * z0) | ((uint_t)f2b(y1 * z1) << 16);
}

// ---------------------------------------------------------------
// weight prep: dst[Npad][K] bf16 = transpose(src[K][N] fp32)
__global__ void k_transcast(const float* __restrict__ src, ushort_t* __restrict__ dst,
                            int K, int N) {
    int n = blockIdx.x;
    for (int k = threadIdx.x; k < K; k += 256) {
        float v = (n < N) ? src[(size_t)k * N + n] : 0.f;
        dst[(size_t)n * K + k] = f2b(v);
    }
}

// patch weights are already [d][k]: direct cast + pad k to 384
__global__ void k_castpad(const float* __restrict__ src, ushort_t* __restrict__ dst) {
    int d = blockIdx.x; int k = threadIdx.x;   // 384 threads
    dst[d * 384 + k] = (k < KPATCH) ? f2b(src[d * KPATCH + k]) : (ushort_t)0;
}

// ---------------------------------------------------------------
// combined out-proj+unembed weight: Wt_comb[n][mp] = nw[mp] * sum_d W_out[mp][d]*W_un[d][n]
// n in [0,384) (rows >=368 zero), mp in [0,512). grid 384, 256 thr.
__global__ void __launch_bounds__(256) k_wcomb(const float* __restrict__ W_out,
                                               const float* __restrict__ W_un,
                                               const float* __restrict__ nw,
                                               ushort_t* __restrict__ Wt) {
    int n = blockIdx.x;
    int tid = threadIdx.x;
    #pragma unroll
    for (int half = 0; half < 2; ++half) {
        int mp = half * 256 + tid;
        float acc = 0.f;
        if (n < KPATCH) {
            const float4* wo4 = (const float4*)(W_out + (size_t)mp * 256);
            #pragma unroll 4
            for (int d4 = 0; d4 < 64; ++d4) {
                float4 wo = wo4[d4];
                int d = d4 * 4;
                acc += wo.x * W_un[(size_t)(d + 0) * KPATCH + n]
                     + wo.y * W_un[(size_t)(d + 1) * KPATCH + n]
                     + wo.z * W_un[(size_t)(d + 2) * KPATCH + n]
                     + wo.w * W_un[(size_t)(d + 3) * KPATCH + n];
            }
            acc *= nw[mp];
        }
        Wt[(size_t)n * 512 + mp] = f2b(acc);
    }
}

// ---------------------------------------------------------------
// fused patch-embed GEMM: xs[BL,256] = gather-im2col(x)[BL,384] @ Wt_p[256][384] + pb.
__global__ void __launch_bounds__(256) k_pgemm(const float* __restrict__ x,
                                               const ushort_t* __restrict__ Wt,
                                               ushort_t* __restrict__ Cv,
                                               const float* __restrict__ bias) {
    __shared__ ushort_t Al[128 * 64];
    __shared__ ushort_t Bl[128 * 64];
    const int tid = threadIdx.x;
    const int w = tid >> 6, lane = tid & 63;
    const int wr = w >> 1, wc = w & 1;
    const int rowbase = blockIdx.y * 128;
    const int colbase = blockIdx.x * 128;
    const int g = lane >> 4, r = lane & 15;
    const int b  = rowbase >> 13;
    const int t  = (rowbase >> 10) & 7;
    const int hp0 = (rowbase >> 5) & 31;

    f32x4 acc[4][4];
    #pragma unroll
    for (int i = 0; i < 4; ++i)
        #pragma unroll
        for (int j = 0; j < 4; ++j) acc[i][j] = (f32x4){0.f, 0.f, 0.f, 0.f};

    for (int it = 0; it < 6; ++it) {        // K=384, BK=64
        int k0 = it * 64;
        __syncthreads();
        #pragma unroll
        for (int i2 = 0; i2 < 4; ++i2) {
            int s = i2 * 256 + (w << 6) + lane;
            int row = s >> 3;
            int c16 = (s & 7) ^ (row & 7);
            gload_lds16(Wt + (size_t)(colbase + row) * 384 + k0 + c16 * 8,
                        &Bl[(size_t)(i2 * 256 + (w << 6)) * 8]);
        }
        #pragma unroll
        for (int i2 = 0; i2 < 8; ++i2) {
            int idx = i2 * 256 + tid;
            int row = idx >> 4, kq = idx & 15;
            int c = (k0 >> 4) + (kq >> 2);
            int i = kq & 3;
            uint_t u0 = 0, u1 = 0;
            if (c < C_INCH) {
                int hp = hp0 + (row >> 5), wp = row & 31;
                const float4 v = *(const float4*)&x[(((size_t)(b * C_INCH + c) * T_N + t) << 14)
                                                    + (size_t)(hp * 4 + i) * W_IMG + wp * 4];
                u0 = (uint_t)f2b(v.x) | ((uint_t)f2b(v.y) << 16);
                u1 = (uint_t)f2b(v.z) | ((uint_t)f2b(v.w) << 16);
            }
            int slot = (row << 3) + ((kq >> 1) ^ (row & 7));
            *(uint2*)&Al[(size_t)slot * 8 + (kq & 1) * 4] = make_uint2(u0, u1);
        }
        __syncthreads();

        short8 af[2][4], bf[2][4];
        #pragma unroll
        for (int ks = 0; ks < 2; ++ks)
            #pragma unroll
            for (int mi = 0; mi < 4; ++mi) {
                int row = (wr << 6) + (mi << 4) + r;
                int c16 = ((ks << 2) | g) ^ (row & 7);
                af[ks][mi] = *(const short8*)&Al[(size_t)((row << 3) + c16) * 8];
            }
        #pragma unroll
        for (int ks = 0; ks < 2; ++ks)
            #pragma unroll
            for (int ni = 0; ni < 4; ++ni) {
                int row = (wc << 6) + (ni << 4) + r;
                int c16 = ((ks << 2) | g) ^ (row & 7);
                bf[ks][ni] = *(const short8*)&Bl[(size_t)((row << 3) + c16) * 8];
            }
        #pragma unroll
        for (int ks = 0; ks < 2; ++ks)
            #pragma unroll
            for (int mi = 0; mi < 4; ++mi)
                #pragma unroll
                for (int ni = 0; ni < 4; ++ni)
                    acc[mi][ni] = __builtin_amdgcn_mfma_f32_16x16x32_bf16(
                        af[ks][mi], bf[ks][ni], acc[mi][ni], 0, 0, 0);
    }

    #pragma unroll
    for (int mi = 0; mi < 4; ++mi) {
        int rw = rowbase + (wr << 6) + (mi << 4) + (g << 2);
        #pragma unroll
        for (int ni = 0; ni < 4; ++ni) {
            int col = colbase + (wc << 6) + (ni << 4) + r;
            float bv = bias[col];
            f32x4 v = acc[mi][ni];
            #pragma unroll
            for (int j = 0; j < 4; ++j)
                Cv[(size_t)(rw + j) * DM_ + col] = f2b(v[j] + bv);
        }
    }
}

// ---------------------------------------------------------------
// MFMA GEMM; ASCALE = fused RMSNorm row-scale; SILU = silu() on outputs.
template <int K, int N, bool CBF, bool ASCALE, bool SILU>
__global__ void __launch_bounds__(256) k_mgemm(const ushort_t* __restrict__ A, const int lda,
                                               const ushort_t* __restrict__ Wt,
                                               void* __restrict__ Cv, const int ldc, const int coff,
                                               const float* __restrict__ bias) {
    __shared__ ushort_t Al[128 * 64];
    __shared__ ushort_t Bl[128 * 64];
    const int tid = threadIdx.x;
    const int w = tid >> 6, lane = tid & 63;
    const int wr = w >> 1, wc = w & 1;
    const int rowbase = blockIdx.y * 128;
    const int colbase = blockIdx.x * 128;
    const int g = lane >> 4, r = lane & 15;

    f32x4 acc[4][4];
    #pragma unroll
    for (int i = 0; i < 4; ++i)
        #pragma unroll
        for (int j = 0; j < 4; ++j) acc[i][j] = (f32x4){0.f, 0.f, 0.f, 0.f};
    float rs[4] = {0.f, 0.f, 0.f, 0.f};

    for (int k0 = 0; k0 < K; k0 += 64) {
        __syncthreads();
        #pragma unroll
        for (int it = 0; it < 4; ++it) {
            int s = it * 256 + (w << 6) + lane;
            int row = s >> 3;
            int c16 = (s & 7) ^ (row & 7);
            gload_lds16(A + (size_t)(rowbase + row) * lda + k0 + c16 * 8,
                        &Al[(size_t)(it * 256 + (w << 6)) * 8]);
        }
        #pragma unroll
        for (int it = 0; it < 4; ++it) {
            int s = it * 256 + (w << 6) + lane;
            int row = s >> 3;
            int c16 = (s & 7) ^ (row & 7);
            gload_lds16(Wt + (size_t)(colbase + row) * K + k0 + c16 * 8,
                        &Bl[(size_t)(it * 256 + (w << 6)) * 8]);
        }
        __syncthreads();

        short8 af[2][4], bf[2][4];
        #pragma unroll
        for (int ks = 0; ks < 2; ++ks)
            #pragma unroll
            for (int mi = 0; mi < 4; ++mi) {
                int row = (wr << 6) + (mi << 4) + r;
                int c16 = ((ks << 2) | g) ^ (row & 7);
                af[ks][mi] = *(const short8*)&Al[(size_t)((row << 3) + c16) * 8];
            }
        #pragma unroll
        for (int ks = 0; ks < 2; ++ks)
            #pragma unroll
            for (int ni = 0; ni < 4; ++ni) {
                int row = (wc << 6) + (ni << 4) + r;
                int c16 = ((ks << 2) | g) ^ (row & 7);
                bf[ks][ni] = *(const short8*)&Bl[(size_t)((row << 3) + c16) * 8];
            }
        if (ASCALE) {
            #pragma unroll
            for (int ks = 0; ks < 2; ++ks)
                #pragma unroll
                for (int mi = 0; mi < 4; ++mi)
                    #pragma unroll
                    for (int e = 0; e < 8; ++e) {
                        float v = b2f((ushort_t)af[ks][mi][e]);
                        rs[mi] += v * v;
                    }
        }
        #pragma unroll
        for (int ks = 0; ks < 2; ++ks)
            #pragma unroll
            for (int mi = 0; mi < 4; ++mi)
                #pragma unroll
                for (int ni = 0; ni < 4; ++ni)
                    acc[mi][ni] = __builtin_amdgcn_mfma_f32_16x16x32_bf16(
                        af[ks][mi], bf[ks][ni], acc[mi][ni], 0, 0, 0);
    }

    #pragma unroll
    for (int mi = 0; mi < 4; ++mi) {
        int rw = rowbase + (wr << 6) + (mi << 4) + (g << 2);
        float sj[4] = {1.f, 1.f, 1.f, 1.f};
        if (ASCALE) {
            float s = rs[mi];
            s += __shfl_xor(s, 16);
            s += __shfl_xor(s, 32);
            float sc = rsqrtf(s * (1.f / 512.f) + 1e-5f);
            #pragma unroll
            for (int j = 0; j < 4; ++j) sj[j] = __shfl(sc, 4 * g + j);
        }
        #pragma unroll
        for (int ni = 0; ni < 4; ++ni) {
            int col = colbase + (wc << 6) + (ni << 4) + r;
            if (col < N) {
                float bv = bias ? bias[col] : 0.f;
                f32x4 v = acc[mi][ni];
                #pragma unroll
                for (int j = 0; j < 4; ++j) {
                    size_t cidx = (size_t)(rw + j) * ldc + coff + col;
                    float vr = v[j] * sj[j] + bv;
                    if (SILU) vr = vr / (1.f + __expf(-vr));
                    if (CBF) ((ushort_t*)Cv)[cidx] = f2b(vr);
                    else     ((float*)Cv)[cidx]   = vr;
                }
            }
        }
    }
}

// ---------------------------------------------------------------
// causal depthwise conv + silu; brec: B[0..15] C[16..31] dA[32..39] dt[40..47] ldA[48..55]
__global__ void __launch_bounds__(256) k_conv(const ushort_t* __restrict__ xbcdt,
                                              const float* __restrict__ cw,
                                              const float* __restrict__ cb,
                                              const float* __restrict__ dtb,
                                              const float* __restrict__ alog,
                                              ushort_t* __restrict__ xbc,
                                              float* __restrict__ brec) {
    int tid = threadIdx.x;
    int rb = blockIdx.x * 8;
    int srb = rb & (L_SEQ - 1);
    #pragma unroll
    for (int it = 0; it < 3; ++it) {
        int ch = it * 256 + tid;
        if (ch >= 552) break;
        if (ch < CONV_DIM_) {
            float w0 = cw[ch * 4 + 0], w1 = cw[ch * 4 + 1];
            float w2 = cw[ch * 4 + 2], w3 = cw[ch * 4 + 3];
            float bias = cb[ch];
            float win[11];
            #pragma unroll
            for (int j = 0; j < 11; ++j) {
                int sj = srb + j - 3;
                win[j] = (sj >= 0) ? b2f(xbcdt[(size_t)(rb + j - 3) * 640 + ch]) : 0.f;
            }
            #pragma unroll
            for (int r = 0; r < 8; ++r) {
                float acc = bias + win[r] * w0 + win[r + 1] * w1 + win[r + 2] * w2 + win[r + 3] * w3;
                float s = acc / (1.f + __expf(-acc));
                size_t row = rb + r;
                if (ch < 512) xbc[row * 512 + ch] = f2b(s);
                else          brec[row * RECW + (ch - 512)] = s;
            }
        } else {
            int h = ch - CONV_DIM_;
            float A = -__expf(alog[h]);
            float db = dtb[h];
            #pragma unroll
            for (int r = 0; r < 8; ++r) {
                size_t row = rb + r;
                float v = b2f(xbcdt[row * 640 + ch]) + db;
                float sp = (v > 20.f) ? v : log1pf(__expf(v));
                brec[row * RECW + 32 + h] = __expf(sp * A);   // dA
                brec[row * RECW + 40 + h] = sp;               // dt
                brec[row * RECW + 48 + h] = sp * A;           // ldA (log decay)
            }
        }
    }
}

// ---------------------------------------------------------------
// stage XhT[p][j] for one chunk using all 256 threads.
__device__ __forceinline__ void stage_xht(const ushort_t* __restrict__ xbc,
                                          size_t row0, int h, int tid,
                                          ushort_t* __restrict__ XhT) {
    int j = tid & 63, q4 = tid >> 6;
    const uint4* xsrc = (const uint4*)(xbc + (row0 + j) * 512 + h * 64);
    uint4 xa = xsrc[q4 * 2], xb = xsrc[q4 * 2 + 1];
    #pragma unroll
    for (int pp = 0; pp < 16; ++pp) {
        int p = q4 * 16 + pp;
        uint4 v = (pp < 8) ? xa : xb;
        int sub = (pp >> 1) & 3;
        uint_t word = (sub == 0) ? v.x : (sub == 1) ? v.y : (sub == 2) ? v.z : v.w;
        XhT[p * 72 + j] = (ushort_t)((pp & 1) ? (word >> 16) : (word & 0xffffu));
    }
}

// ---------------------------------------------------------------
// scan phase 1 via MFMA (4 waves/block; wave w owns p-tile p0t=w).
__global__ void __launch_bounds__(256) k_scan1m(const ushort_t* __restrict__ xbc,
                                                const float* __restrict__ brec,
                                                float* __restrict__ sbuf,
                                                float* __restrict__ cdf) {
    __shared__ ushort_t XhT[64 * 72];
    __shared__ float    Bst[64 * 20];
    __shared__ ushort_t BwT[16 * 72];
    const int c = blockIdx.x, h = blockIdx.y, b = blockIdx.z;
    const int tid = threadIdx.x;
    const int w = tid >> 6, lane = tid & 63;
    const int g = lane >> 4, r = lane & 15;
    const size_t row0 = (size_t)b * L_SEQ + (size_t)c * QCH;

    {
        int row = tid >> 2, q = tid & 3;
        float4 v = *(const float4*)(brec + (row0 + row) * RECW + q * 4);
        *(float4*)&Bst[row * 20 + q * 4] = v;
    }
    stage_xht(xbc, row0, h, tid, XhT);

    if (w == 0) {
        float ldA = brec[(row0 + lane) * RECW + 48 + h];
        float dtv = brec[(row0 + lane) * RECW + 40 + h];
        float S = ldA;
        #pragma unroll
        for (int d = 1; d < 64; d <<= 1) {
            float o = __shfl(S, (lane >= d) ? (lane - d) : 0);
            if (lane >= d) S += o;
        }
        float Stot = __shfl(S, 63);
        float wj = dtv * __expf(Stot - S);
        __builtin_amdgcn_s_barrier();
        const float* bp = &Bst[lane * 20];
        float4 b0 = *(const float4*)bp;
        float4 b1 = *(const float4*)(bp + 4);
        float4 b2 = *(const float4*)(bp + 8);
        float4 b3 = *(const float4*)(bp + 12);
        float bv[16] = {b0.x,b0.y,b0.z,b0.w, b1.x,b1.y,b1.z,b1.w,
                        b2.x,b2.y,b2.z,b2.w, b3.x,b3.y,b3.z,b3.w};
        #pragma unroll
        for (int n = 0; n < 16; ++n)
            BwT[n * 72 + lane] = f2b(bv[n] * wj);
        if (lane == 63) cdf[(b * 8 + h) * NCH + c] = __expf(S);
    } else {
        __builtin_amdgcn_s_barrier();
    }
    __syncthreads();

    short8 bwtf[2];
    bwtf[0] = *(const short8*)&BwT[r * 72 + 0  + g * 8];
    bwtf[1] = *(const short8*)&BwT[r * 72 + 32 + g * 8];

    size_t base = ((size_t)(b * 8 + h) * NCH + c) * 1024;
    {
        int p0t = w;
        short8 a0 = *(const short8*)&XhT[(p0t * 16 + r) * 72 + 0  + g * 8];
        short8 a1 = *(const short8*)&XhT[(p0t * 16 + r) * 72 + 32 + g * 8];
        f32x4 acc = (f32x4){0.f, 0.f, 0.f, 0.f};
        acc = __builtin_amdgcn_mfma_f32_16x16x32_bf16(a0, bwtf[0], acc, 0, 0, 0);
        acc = __builtin_amdgcn_mfma_f32_16x16x32_bf16(a1, bwtf[1], acc, 0, 0, 0);
        #pragma unroll
        for (int reg = 0; reg < 4; ++reg)
            sbuf[base + (size_t)(p0t * 16 + g * 4 + reg) * 16 + r] = acc[reg];
    }
}

// ---------------------------------------------------------------
// phase 2: sequential chain over chunks; 4-deep batched prefetch.
__global__ void __launch_bounds__(256) k_chain(const float* __restrict__ sbuf,
                                               const float* __restrict__ cdf,
                                               float* __restrict__ hin) {
    int h = blockIdx.x, b = blockIdx.y;
    int tid = threadIdx.x;
    float4 H = make_float4(0.f, 0.f, 0.f, 0.f);
    size_t base = (size_t)((b * 8 + h) * NCH) * 1024;
    const float* cdp = cdf + (size_t)(b * 8 + h) * NCH;
    for (int c0 = 0; c0 < NCH; c0 += 4) {
        float4 S[4];
        float cd[4];
        #pragma unroll
        for (int j = 0; j < 4; ++j) {
            S[j]  = *(const float4*)&sbuf[base + (size_t)(c0 + j) * 1024 + tid * 4];
            cd[j] = cdp[c0 + j];
        }
        #pragma unroll
        for (int j = 0; j < 4; ++j) {
            *(float4*)&hin[base + (size_t)(c0 + j) * 1024 + tid * 4] = H;
            H.x = cd[j] * H.x + S[j].x;
            H.y = cd[j] * H.y + S[j].y;
            H.z = cd[j] * H.z + S[j].z;
            H.w = cd[j] * H.w + S[j].w;
        }
    }
}

// ---------------------------------------------------------------
// SSD scan phase 3 via MFMA (4 waves/block; wave w owns i-tile i0t=w).
// z_bf holds PRE-SILU'd z. Pre-gate y staged bf16 in LDS; vectorized gate+store pass.
__global__ void __launch_bounds__(256) k_ssc2(const ushort_t* __restrict__ xbc,
                                              const ushort_t* __restrict__ z_bf,
                                              const float* __restrict__ brec,
                                              const float* __restrict__ Dp,
                                              const float* __restrict__ hin,
                                              ushort_t* __restrict__ yg_out) {
    __shared__ ushort_t XhT[64 * 72];
    __shared__ ushort_t Pl [64 * 72];   // recBC [64][40] -> P [i][j] -> Y [i][p]
    __shared__ float Sl[64], Tl[64], El[64];
    const int c = blockIdx.x, h = blockIdx.y, b = blockIdx.z;
    const int tid = threadIdx.x;
    const int w = tid >> 6, lane = tid & 63;
    const int g = lane >> 4, r = lane & 15;
    const size_t row0 = (size_t)b * L_SEQ + (size_t)c * QCH;
    const size_t bhc = (size_t)(b * 8 + h) * NCH + c;

    // stage B+C coalesced -> bf16 recBC (stride 40)
    #pragma unroll
    for (int it2 = 0; it2 < 2; ++it2) {
        int idx = it2 * 256 + tid;
        int row = idx >> 3, q = idx & 7;
        float4 v = *(const float4*)(brec + (row0 + row) * RECW + q * 4);
        uint_t u0 = (uint_t)f2b(v.x) | ((uint_t)f2b(v.y) << 16);
        uint_t u1 = (uint_t)f2b(v.z) | ((uint_t)f2b(v.w) << 16);
        *(uint2*)&Pl[row * 40 + q * 4] = make_uint2(u0, u1);
    }
    stage_xht(xbc, row0, h, tid, XhT);

    if (w == 0) {
        float ldA = brec[(row0 + lane) * RECW + 48 + h];
        float dtv = brec[(row0 + lane) * RECW + 40 + h];
        float S = ldA;
        #pragma unroll
        for (int d = 1; d < 64; d <<= 1) {
            float o = __shfl(S, (lane >= d) ? (lane - d) : 0);
            if (lane >= d) S += o;
        }
        Sl[lane] = S;
        Tl[lane] = S - __logf(dtv);
        El[lane] = __expf(S);
    }
    __syncthreads();

    // frags: all bwf, own cwf only (K padded 16->32, g>=2 zero)
    short8 cwf, bwf[4];
    #pragma unroll
    for (int t4 = 0; t4 < 4; ++t4) {
        if (g < 2) {
            bwf[t4] = *(const short8*)&Pl[(t4 * 16 + r) * 40 + 0 + g * 8];
        } else {
            #pragma unroll
            for (int e = 0; e < 8; ++e) bwf[t4][e] = 0;
        }
    }
    if (g < 2) {
        cwf = *(const short8*)&Pl[(w * 16 + r) * 40 + 16 + g * 8];
    } else {
        #pragma unroll
        for (int e = 0; e < 8; ++e) cwf[e] = 0;
    }
    __syncthreads();   // frags hoisted before Pl overwritten

    // ---- MFMA-1: wave w computes i-tile i0t=w -> P rows i=w*16+r
    {
        int i = w * 16 + r;
        float si = Sl[i];
        #pragma unroll
        for (int j0t = 0; j0t < 4; ++j0t) {
            f32x4 m = (f32x4){0.f, 0.f, 0.f, 0.f};
            m = __builtin_amdgcn_mfma_f32_16x16x32_bf16(bwf[j0t], cwf, m, 0, 0, 0);
            float4 tj = *(const float4*)&Tl[j0t * 16 + g * 4];
            ushort_t pv[4];
            #pragma unroll
            for (int reg = 0; reg < 4; ++reg) {
                int j = j0t * 16 + g * 4 + reg;
                float tjv = (reg == 0) ? tj.x : (reg == 1) ? tj.y : (reg == 2) ? tj.z : tj.w;
                float mask = (j <= i) ? __expf(si - tjv) : 0.f;
                pv[reg] = f2b(m[reg] * mask);
            }
            uint2 packed = make_uint2((uint_t)pv[0] | ((uint_t)pv[1] << 16),
                                      (uint_t)pv[2] | ((uint_t)pv[3] << 16));
            *(uint2*)&Pl[i * 72 + j0t * 16 + g * 4] = packed;
        }
    }
    __syncthreads();

    // hoist P-frags (own rows), Xh frags, Hin frags
    short8 pa0 = *(const short8*)&Pl[(w * 16 + r) * 72 + 0  + g * 8];
    short8 pa1 = *(const short8*)&Pl[(w * 16 + r) * 72 + 32 + g * 8];
    short8 xhf[4][2];
    #pragma unroll
    for (int p0t = 0; p0t < 4; ++p0t)
        #pragma unroll
        for (int kk = 0; kk < 2; ++kk)
            xhf[p0t][kk] = *(const short8*)&XhT[(p0t * 16 + r) * 72 + kk * 32 + g * 8];
    short8 hinf[4];
    #pragma unroll
    for (int p0t = 0; p0t < 4; ++p0t)
        hinf[p0t] = frag8(hin + bhc * 1024 + (size_t)(p0t * 16 + r) * 16 + g * 8, g < 2);

    const float Dh = Dp[h];
    float4 e4 = *(const float4*)&El[w * 16 + g * 4];
    __syncthreads();   // all P-frags hoisted before Pl is overwritten with Y

    // ---- compute y (pre-gate), write bf16 into Pl[i][p] (stride 72)
    #pragma unroll
    for (int p0t = 0; p0t < 4; ++p0t) {
        f32x4 acc = (f32x4){0.f, 0.f, 0.f, 0.f};
        acc = __builtin_amdgcn_mfma_f32_16x16x32_bf16(cwf, hinf[p0t], acc, 0, 0, 0);
        acc[0] *= e4.x; acc[1] *= e4.y; acc[2] *= e4.z; acc[3] *= e4.w;
        acc = __builtin_amdgcn_mfma_f32_16x16x32_bf16(pa0, xhf[p0t][0], acc, 0, 0, 0);
        acc = __builtin_amdgcn_mfma_f32_16x16x32_bf16(pa1, xhf[p0t][1], acc, 0, 0, 0);
        int p = p0t * 16 + r;
        #pragma unroll
        for (int reg = 0; reg < 4; ++reg) {
            int i = w * 16 + g * 4 + reg;
            float xhv = b2f(XhT[p * 72 + i]);
            Pl[i * 72 + p] = f2b(acc[reg] + Dh * xhv);
        }
    }
    __syncthreads();

    // ---- vectorized gate + store: 512 (row, 8-col-seg) items over 256 threads
    #pragma unroll
    for (int it6 = 0; it6 < 2; ++it6) {
        int t = it6 * 256 + tid;
        int i = t >> 3, seg = t & 7;
        size_t row = row0 + i;
        uint4 yv = *(const uint4*)&Pl[i * 72 + seg * 8];
        uint4 zv = *(const uint4*)(z_bf + row * 512 + h * 64 + seg * 8);
        uint4 ov;
        ov.x = gate2(yv.x, zv.x);
        ov.y = gate2(yv.y, zv.y);
        ov.z = gate2(yv.z, zv.z);
        ov.w = gate2(yv.w, zv.w);
        *(uint4*)(yg_out + row * 512 + h * 64 + seg * 8) = ov;
    }
}

// ---------------------------------------------------------------
__global__ void __launch_bounds__(256) k_scatter(const ushort_t* __restrict__ tmp,
                                                 const float* __restrict__ ub,
                                                 const float* __restrict__ xin,
                                                 float* __restrict__ out) {
    int tid = threadIdx.x;
    int w = tid & 127;
    int h = (blockIdx.x << 1) | (tid >> 7);
    int c = blockIdx.y >> 3, t = blockIdx.y & 7;
    int b = blockIdx.z;
    size_t row = (size_t)b * L_SEQ + t * 1024 + (h >> 2) * 32 + (w >> 2);
    int kk = c * 16 + (h & 3) * 4 + (w & 3);
    size_t oidx = (((size_t)(b * C_INCH + c) * T_N + t) << 14) + (size_t)h * W_IMG + w;
    out[oidx] = b2f(tmp[row * KPATCH + kk]) + ub[c] + xin[oidx];
}

// ---------------------------------------------------------------
extern "C" void kernel_launch(void* const* d_in, const int* in_sizes, int n_in,
                              void* d_out, int out_size, void* d_ws, size_t ws_size,
                              hipStream_t stream) {
    const float* x       = (const float*)d_in[0];
    const float* patch_w = (const float*)d_in[1];
    const float* patch_b = (const float*)d_in[2];
    const float* W_in    = (const float*)d_in[3];
    const float* conv_w  = (const float*)d_in[4];
    const float* conv_b  = (const float*)d_in[5];
    const float* dt_bias = (const float*)d_in[6];
    const float* A_log   = (const float*)d_in[7];
    const float* D_param = (const float*)d_in[8];
    const float* norm_w  = (const float*)d_in[9];
    const float* W_out   = (const float*)d_in[10];
    const float* unemb_w = (const float*)d_in[11];
    const float* unemb_b = (const float*)d_in[12];
    float* out = (float*)d_out;

    // ---- workspace carve ----
    char* p = (char*)d_ws;
    ushort_t* scratch = (ushort_t*)p; p += (size_t)BLROWS * 384 * 2;   // 25 MB (bf16 tmp)
    float* cdf  = (float*)p;   p += (size_t)32 * NCH * 4;
    float* sbuf = (float*)p;   p += (size_t)32 * NCH * 1024 * 4;       // 16.8 MB
    float* hin  = (float*)p;   p += (size_t)32 * NCH * 1024 * 4;       // 16.8 MB
    float* brec = (float*)p;   p += (size_t)BLROWS * RECW * 4;         // 7.3 MB
    ushort_t* Wt_p    = (ushort_t*)p; p += (size_t)256 * 384 * 2;
    ushort_t* Wt_in   = (ushort_t*)p; p += (size_t)1152 * 256 * 2;
    ushort_t* Wt_comb = (ushort_t*)p; p += (size_t)384 * 512 * 2;      // fused out-proj+unembed
    ushort_t* xs     = (ushort_t*)p; p += (size_t)BLROWS * DM_ * 2;    // 16.8 MB
    ushort_t* xbc    = (ushort_t*)p; p += (size_t)BLROWS * 512 * 2;    // 33.5 MB
    ushort_t* z_bf   = (ushort_t*)p; p += (size_t)BLROWS * 512 * 2;    // 33.5 MB (silu'd z)
    ushort_t* xbcdt  = (ushort_t*)p; p += (size_t)BLROWS * 640 * 2;    // 41.9 MB (later: yg)
    size_t need = (size_t)(p - (char*)d_ws);
    if (ws_size < need) return;

    ushort_t* tmp = scratch;            // bf16 fused-output [BL][368]
    ushort_t* yg  = xbcdt;              // yg overlays xbcdt (dead after conv)

    k_castpad<<<256, 384, 0, stream>>>(patch_w, Wt_p);
    k_transcast<<<1152, 256, 0, stream>>>(W_in, Wt_in, 256, 1064);
    k_wcomb<<<384, 256, 0, stream>>>(W_out, unemb_w, norm_w, Wt_comb);

    // fused im2col + patch GEMM
    k_pgemm<<<dim3(2, 256), 256, 0, stream>>>(x, Wt_p, xs, patch_b);

    // in-proj split: silu(z) cols 0..511 -> z_bf; xBC+dt cols 512..1063 -> xbcdt
    k_mgemm<256, 512, true, false, true><<<dim3(4, 256), 256, 0, stream>>>(xs, 256, Wt_in, z_bf, 512, 0, nullptr);
    k_mgemm<256, 552, true, false, false><<<dim3(5, 256), 256, 0, stream>>>(xs, 256, Wt_in + (size_t)512 * 256, xbcdt, 640, 0, nullptr);

    k_conv<<<BLROWS / 8, 256, 0, stream>>>(xbcdt, conv_w, conv_b, dt_bias, A_log, xbc, brec);

    k_scan1m<<<dim3(NCH, 8, 4), 256, 0, stream>>>(xbc, brec, sbuf, cdf);
    k_chain<<<dim3(8, 4), 256, 0, stream>>>(sbuf, cdf, hin);
    k_ssc2<<<dim3(NCH, 8, 4), 256, 0, stream>>>(xbc, z_bf, brec, D_param, hin, yg);

    // fused out-proj + RMSNorm + unembed: tmp[BL,368] = rms(yg) @ Wt_comb
    k_mgemm<512, 368, true, true, false><<<dim3(3, 256), 256, 0, stream>>>(yg, 512, Wt_comb, tmp, KPATCH, 0, nullptr);

    k_scatter<<<dim3(64, 184, 4), 256, 0, stream>>>(tmp, unemb_b, x, out);
}

// Round 18
// 269.621 us; speedup vs baseline: 1.0575x; 1.0575x over previous
//
#include <hip/hip_runtime.h>
#include <hip/hip_bf16.h>
#include <cstdint>
#include <cstddef>

// ---- problem constants ----
#define B_N       4
#define C_INCH    23
#define T_N       8
#define W_IMG     128
#define L_SEQ     8192
#define BLROWS    32768      // B_N * L_SEQ
#define DM_       256
#define D_INNER_  512
#define CONV_DIM_ 544
#define D_PROJ    1064
#define KPATCH    368        // C_INCH*4*4
#define QCH       64         // scan chunk length
#define NCH       128        // chunks per batch
#define RECW      56         // packed scan record (floats): B16 C16 dA8 dt8 ldA8

typedef unsigned short ushort_t;
typedef unsigned int uint_t;
typedef __attribute__((ext_vector_type(8))) short short8;
typedef __attribute__((ext_vector_type(4))) float f32x4;

__device__ __forceinline__ float b2f(ushort_t u) {
    union { float f; uint_t u; } v; v.u = ((uint_t)u) << 16; return v.f;
}
__device__ __forceinline__ ushort_t f2b(float f) {
    union { float f; uint_t u; } v; v.f = f;
    uint_t r = v.u + 0x7fffu + ((v.u >> 16) & 1u);
    return (ushort_t)(r >> 16);
}

// async global->LDS, 16B per lane. LDS dest = wave-uniform base + lane*16.
__device__ __forceinline__ void gload_lds16(const ushort_t* g, ushort_t* l) {
    __builtin_amdgcn_global_load_lds(
        (const __attribute__((address_space(1))) unsigned int*)g,
        (__attribute__((address_space(3))) unsigned int*)l, 16, 0, 0);
}

// build a bf16 short8 frag from 8 consecutive f32 (or zeros if !live)
__device__ __forceinline__ short8 frag8(const float* q, bool live) {
    short8 f;
    if (live) {
        float4 lo = *(const float4*)q, hi = *(const float4*)(q + 4);
        f[0] = (short)f2b(lo.x); f[1] = (short)f2b(lo.y);
        f[2] = (short)f2b(lo.z); f[3] = (short)f2b(lo.w);
        f[4] = (short)f2b(hi.x); f[5] = (short)f2b(hi.y);
        f[6] = (short)f2b(hi.z); f[7] = (short)f2b(hi.w);
    } else {
        #pragma unroll
        for (int e = 0; e < 8; ++e) f[e] = 0;
    }
    return f;
}

// gate one packed pair: out = pack(bf16(y0*z0), bf16(y1*z1))
__device__ __forceinline__ uint_t gate2(uint_t yw, uint_t zw) {
    float y0 = b2f((ushort_t)(yw & 0xffffu)), y1 = b2f((ushort_t)(yw >> 16));
    float z0 = b2f((ushort_t)(zw & 0xffffu)), z1 = b2f((ushort_t)(zw >> 16));
    return (uint_t)f2b(y0 * z0) | ((uint_t)f2b(y1 * z1) << 16);
}

// ---------------------------------------------------------------
// weight prep: dst[Npad][K] bf16 = transpose(src[K][N] fp32)
__global__ void k_transcast(const float* __restrict__ src, ushort_t* __restrict__ dst,
                            int K, int N) {
    int n = blockIdx.x;
    for (int k = threadIdx.x; k < K; k += 256) {
        float v = (n < N) ? src[(size_t)k * N + n] : 0.f;
        dst[(size_t)n * K + k] = f2b(v);
    }
}

// patch weights are already [d][k]: direct cast + pad k to 384
__global__ void k_castpad(const float* __restrict__ src, ushort_t* __restrict__ dst) {
    int d = blockIdx.x; int k = threadIdx.x;   // 384 threads
    dst[d * 384 + k] = (k < KPATCH) ? f2b(src[d * KPATCH + k]) : (ushort_t)0;
}

// Wt_os[mp][d] bf16 = nw[mp] * W_out[mp][d]  (coalesced)
__global__ void __launch_bounds__(256) k_scaleW(const float* __restrict__ W_out,
                                                const float* __restrict__ nw,
                                                ushort_t* __restrict__ dst) {
    int mp = blockIdx.x;
    float s = nw[mp];
    int d = threadIdx.x;
    dst[(size_t)mp * 256 + d] = f2b(W_out[(size_t)mp * 256 + d] * s);
}

// ---------------------------------------------------------------
// fused patch-embed GEMM: xs[BL,256] = gather-im2col(x)[BL,384] @ Wt_p[256][384] + pb.
__global__ void __launch_bounds__(256) k_pgemm(const float* __restrict__ x,
                                               const ushort_t* __restrict__ Wt,
                                               ushort_t* __restrict__ Cv,
                                               const float* __restrict__ bias) {
    __shared__ ushort_t Al[128 * 64];
    __shared__ ushort_t Bl[128 * 64];
    const int tid = threadIdx.x;
    const int w = tid >> 6, lane = tid & 63;
    const int wr = w >> 1, wc = w & 1;
    const int rowbase = blockIdx.y * 128;
    const int colbase = blockIdx.x * 128;
    const int g = lane >> 4, r = lane & 15;
    const int b  = rowbase >> 13;
    const int t  = (rowbase >> 10) & 7;
    const int hp0 = (rowbase >> 5) & 31;

    f32x4 acc[4][4];
    #pragma unroll
    for (int i = 0; i < 4; ++i)
        #pragma unroll
        for (int j = 0; j < 4; ++j) acc[i][j] = (f32x4){0.f, 0.f, 0.f, 0.f};

    for (int it = 0; it < 6; ++it) {        // K=384, BK=64
        int k0 = it * 64;
        __syncthreads();
        #pragma unroll
        for (int i2 = 0; i2 < 4; ++i2) {
            int s = i2 * 256 + (w << 6) + lane;
            int row = s >> 3;
            int c16 = (s & 7) ^ (row & 7);
            gload_lds16(Wt + (size_t)(colbase + row) * 384 + k0 + c16 * 8,
                        &Bl[(size_t)(i2 * 256 + (w << 6)) * 8]);
        }
        #pragma unroll
        for (int i2 = 0; i2 < 8; ++i2) {
            int idx = i2 * 256 + tid;
            int row = idx >> 4, kq = idx & 15;
            int c = (k0 >> 4) + (kq >> 2);
            int i = kq & 3;
            uint_t u0 = 0, u1 = 0;
            if (c < C_INCH) {
                int hp = hp0 + (row >> 5), wp = row & 31;
                const float4 v = *(const float4*)&x[(((size_t)(b * C_INCH + c) * T_N + t) << 14)
                                                    + (size_t)(hp * 4 + i) * W_IMG + wp * 4];
                u0 = (uint_t)f2b(v.x) | ((uint_t)f2b(v.y) << 16);
                u1 = (uint_t)f2b(v.z) | ((uint_t)f2b(v.w) << 16);
            }
            int slot = (row << 3) + ((kq >> 1) ^ (row & 7));
            *(uint2*)&Al[(size_t)slot * 8 + (kq & 1) * 4] = make_uint2(u0, u1);
        }
        __syncthreads();

        short8 af[2][4], bf[2][4];
        #pragma unroll
        for (int ks = 0; ks < 2; ++ks)
            #pragma unroll
            for (int mi = 0; mi < 4; ++mi) {
                int row = (wr << 6) + (mi << 4) + r;
                int c16 = ((ks << 2) | g) ^ (row & 7);
                af[ks][mi] = *(const short8*)&Al[(size_t)((row << 3) + c16) * 8];
            }
        #pragma unroll
        for (int ks = 0; ks < 2; ++ks)
            #pragma unroll
            for (int ni = 0; ni < 4; ++ni) {
                int row = (wc << 6) + (ni << 4) + r;
                int c16 = ((ks << 2) | g) ^ (row & 7);
                bf[ks][ni] = *(const short8*)&Bl[(size_t)((row << 3) + c16) * 8];
            }
        #pragma unroll
        for (int ks = 0; ks < 2; ++ks)
            #pragma unroll
            for (int mi = 0; mi < 4; ++mi)
                #pragma unroll
                for (int ni = 0; ni < 4; ++ni)
                    acc[mi][ni] = __builtin_amdgcn_mfma_f32_16x16x32_bf16(
                        af[ks][mi], bf[ks][ni], acc[mi][ni], 0, 0, 0);
    }

    #pragma unroll
    for (int mi = 0; mi < 4; ++mi) {
        int rw = rowbase + (wr << 6) + (mi << 4) + (g << 2);
        #pragma unroll
        for (int ni = 0; ni < 4; ++ni) {
            int col = colbase + (wc << 6) + (ni << 4) + r;
            float bv = bias[col];
            f32x4 v = acc[mi][ni];
            #pragma unroll
            for (int j = 0; j < 4; ++j)
                Cv[(size_t)(rw + j) * DM_ + col] = f2b(v[j] + bv);
        }
    }
}

// ---------------------------------------------------------------
// MFMA GEMM; ASCALE = fused RMSNorm row-scale; SILU = silu() on outputs.
template <int K, int N, bool CBF, bool ASCALE, bool SILU>
__global__ void __launch_bounds__(256) k_mgemm(const ushort_t* __restrict__ A, const int lda,
                                               const ushort_t* __restrict__ Wt,
                                               void* __restrict__ Cv, const int ldc, const int coff,
                                               const float* __restrict__ bias) {
    __shared__ ushort_t Al[128 * 64];
    __shared__ ushort_t Bl[128 * 64];
    const int tid = threadIdx.x;
    const int w = tid >> 6, lane = tid & 63;
    const int wr = w >> 1, wc = w & 1;
    const int rowbase = blockIdx.y * 128;
    const int colbase = blockIdx.x * 128;
    const int g = lane >> 4, r = lane & 15;

    f32x4 acc[4][4];
    #pragma unroll
    for (int i = 0; i < 4; ++i)
        #pragma unroll
        for (int j = 0; j < 4; ++j) acc[i][j] = (f32x4){0.f, 0.f, 0.f, 0.f};
    float rs[4] = {0.f, 0.f, 0.f, 0.f};

    for (int k0 = 0; k0 < K; k0 += 64) {
        __syncthreads();
        #pragma unroll
        for (int it = 0; it < 4; ++it) {
            int s = it * 256 + (w << 6) + lane;
            int row = s >> 3;
            int c16 = (s & 7) ^ (row & 7);
            gload_lds16(A + (size_t)(rowbase + row) * lda + k0 + c16 * 8,
                        &Al[(size_t)(it * 256 + (w << 6)) * 8]);
        }
        #pragma unroll
        for (int it = 0; it < 4; ++it) {
            int s = it * 256 + (w << 6) + lane;
            int row = s >> 3;
            int c16 = (s & 7) ^ (row & 7);
            gload_lds16(Wt + (size_t)(colbase + row) * K + k0 + c16 * 8,
                        &Bl[(size_t)(it * 256 + (w << 6)) * 8]);
        }
        __syncthreads();

        short8 af[2][4], bf[2][4];
        #pragma unroll
        for (int ks = 0; ks < 2; ++ks)
            #pragma unroll
            for (int mi = 0; mi < 4; ++mi) {
                int row = (wr << 6) + (mi << 4) + r;
                int c16 = ((ks << 2) | g) ^ (row & 7);
                af[ks][mi] = *(const short8*)&Al[(size_t)((row << 3) + c16) * 8];
            }
        #pragma unroll
        for (int ks = 0; ks < 2; ++ks)
            #pragma unroll
            for (int ni = 0; ni < 4; ++ni) {
                int row = (wc << 6) + (ni << 4) + r;
                int c16 = ((ks << 2) | g) ^ (row & 7);
                bf[ks][ni] = *(const short8*)&Bl[(size_t)((row << 3) + c16) * 8];
            }
        if (ASCALE) {
            #pragma unroll
            for (int ks = 0; ks < 2; ++ks)
                #pragma unroll
                for (int mi = 0; mi < 4; ++mi)
                    #pragma unroll
                    for (int e = 0; e < 8; ++e) {
                        float v = b2f((ushort_t)af[ks][mi][e]);
                        rs[mi] += v * v;
                    }
        }
        #pragma unroll
        for (int ks = 0; ks < 2; ++ks)
            #pragma unroll
            for (int mi = 0; mi < 4; ++mi)
                #pragma unroll
                for (int ni = 0; ni < 4; ++ni)
                    acc[mi][ni] = __builtin_amdgcn_mfma_f32_16x16x32_bf16(
                        af[ks][mi], bf[ks][ni], acc[mi][ni], 0, 0, 0);
    }

    #pragma unroll
    for (int mi = 0; mi < 4; ++mi) {
        int rw = rowbase + (wr << 6) + (mi << 4) + (g << 2);
        float sj[4] = {1.f, 1.f, 1.f, 1.f};
        if (ASCALE) {
            float s = rs[mi];
            s += __shfl_xor(s, 16);
            s += __shfl_xor(s, 32);
            float sc = rsqrtf(s * (1.f / 512.f) + 1e-5f);
            #pragma unroll
            for (int j = 0; j < 4; ++j) sj[j] = __shfl(sc, 4 * g + j);
        }
        #pragma unroll
        for (int ni = 0; ni < 4; ++ni) {
            int col = colbase + (wc << 6) + (ni << 4) + r;
            if (col < N) {
                float bv = bias ? bias[col] : 0.f;
                f32x4 v = acc[mi][ni];
                #pragma unroll
                for (int j = 0; j < 4; ++j) {
                    size_t cidx = (size_t)(rw + j) * ldc + coff + col;
                    float vr = v[j] * sj[j] + bv;
                    if (SILU) vr = vr / (1.f + __expf(-vr));
                    if (CBF) ((ushort_t*)Cv)[cidx] = f2b(vr);
                    else     ((float*)Cv)[cidx]   = vr;
                }
            }
        }
    }
}

// ---------------------------------------------------------------
// causal depthwise conv + silu; brec: B[0..15] C[16..31] dA[32..39] dt[40..47] ldA[48..55]
__global__ void __launch_bounds__(256) k_conv(const ushort_t* __restrict__ xbcdt,
                                              const float* __restrict__ cw,
                                              const float* __restrict__ cb,
                                              const float* __restrict__ dtb,
                                              const float* __restrict__ alog,
                                              ushort_t* __restrict__ xbc,
                                              float* __restrict__ brec) {
    int tid = threadIdx.x;
    int rb = blockIdx.x * 8;
    int srb = rb & (L_SEQ - 1);
    #pragma unroll
    for (int it = 0; it < 3; ++it) {
        int ch = it * 256 + tid;
        if (ch >= 552) break;
        if (ch < CONV_DIM_) {
            float w0 = cw[ch * 4 + 0], w1 = cw[ch * 4 + 1];
            float w2 = cw[ch * 4 + 2], w3 = cw[ch * 4 + 3];
            float bias = cb[ch];
            float win[11];
            #pragma unroll
            for (int j = 0; j < 11; ++j) {
                int sj = srb + j - 3;
                win[j] = (sj >= 0) ? b2f(xbcdt[(size_t)(rb + j - 3) * 640 + ch]) : 0.f;
            }
            #pragma unroll
            for (int r = 0; r < 8; ++r) {
                float acc = bias + win[r] * w0 + win[r + 1] * w1 + win[r + 2] * w2 + win[r + 3] * w3;
                float s = acc / (1.f + __expf(-acc));
                size_t row = rb + r;
                if (ch < 512) xbc[row * 512 + ch] = f2b(s);
                else          brec[row * RECW + (ch - 512)] = s;
            }
        } else {
            int h = ch - CONV_DIM_;
            float A = -__expf(alog[h]);
            float db = dtb[h];
            #pragma unroll
            for (int r = 0; r < 8; ++r) {
                size_t row = rb + r;
                float v = b2f(xbcdt[row * 640 + ch]) + db;
                float sp = (v > 20.f) ? v : log1pf(__expf(v));
                brec[row * RECW + 32 + h] = __expf(sp * A);   // dA
                brec[row * RECW + 40 + h] = sp;               // dt
                brec[row * RECW + 48 + h] = sp * A;           // ldA (log decay)
            }
        }
    }
}

// ---------------------------------------------------------------
// stage XhT[p][j] for one chunk using all 256 threads.
__device__ __forceinline__ void stage_xht(const ushort_t* __restrict__ xbc,
                                          size_t row0, int h, int tid,
                                          ushort_t* __restrict__ XhT) {
    int j = tid & 63, q4 = tid >> 6;
    const uint4* xsrc = (const uint4*)(xbc + (row0 + j) * 512 + h * 64);
    uint4 xa = xsrc[q4 * 2], xb = xsrc[q4 * 2 + 1];
    #pragma unroll
    for (int pp = 0; pp < 16; ++pp) {
        int p = q4 * 16 + pp;
        uint4 v = (pp < 8) ? xa : xb;
        int sub = (pp >> 1) & 3;
        uint_t word = (sub == 0) ? v.x : (sub == 1) ? v.y : (sub == 2) ? v.z : v.w;
        XhT[p * 72 + j] = (ushort_t)((pp & 1) ? (word >> 16) : (word & 0xffffu));
    }
}

// ---------------------------------------------------------------
// scan phase 1 via MFMA (4 waves/block; wave w owns p-tile p0t=w).
__global__ void __launch_bounds__(256) k_scan1m(const ushort_t* __restrict__ xbc,
                                                const float* __restrict__ brec,
                                                float* __restrict__ sbuf,
                                                float* __restrict__ cdf) {
    __shared__ ushort_t XhT[64 * 72];
    __shared__ float    Bst[64 * 20];
    __shared__ ushort_t BwT[16 * 72];
    const int c = blockIdx.x, h = blockIdx.y, b = blockIdx.z;
    const int tid = threadIdx.x;
    const int w = tid >> 6, lane = tid & 63;
    const int g = lane >> 4, r = lane & 15;
    const size_t row0 = (size_t)b * L_SEQ + (size_t)c * QCH;

    {
        int row = tid >> 2, q = tid & 3;
        float4 v = *(const float4*)(brec + (row0 + row) * RECW + q * 4);
        *(float4*)&Bst[row * 20 + q * 4] = v;
    }
    stage_xht(xbc, row0, h, tid, XhT);

    if (w == 0) {
        float ldA = brec[(row0 + lane) * RECW + 48 + h];
        float dtv = brec[(row0 + lane) * RECW + 40 + h];
        float S = ldA;
        #pragma unroll
        for (int d = 1; d < 64; d <<= 1) {
            float o = __shfl(S, (lane >= d) ? (lane - d) : 0);
            if (lane >= d) S += o;
        }
        float Stot = __shfl(S, 63);
        float wj = dtv * __expf(Stot - S);
        __builtin_amdgcn_s_barrier();
        const float* bp = &Bst[lane * 20];
        float4 b0 = *(const float4*)bp;
        float4 b1 = *(const float4*)(bp + 4);
        float4 b2 = *(const float4*)(bp + 8);
        float4 b3 = *(const float4*)(bp + 12);
        float bv[16] = {b0.x,b0.y,b0.z,b0.w, b1.x,b1.y,b1.z,b1.w,
                        b2.x,b2.y,b2.z,b2.w, b3.x,b3.y,b3.z,b3.w};
        #pragma unroll
        for (int n = 0; n < 16; ++n)
            BwT[n * 72 + lane] = f2b(bv[n] * wj);
        if (lane == 63) cdf[(b * 8 + h) * NCH + c] = __expf(S);
    } else {
        __builtin_amdgcn_s_barrier();
    }
    __syncthreads();

    short8 bwtf[2];
    bwtf[0] = *(const short8*)&BwT[r * 72 + 0  + g * 8];
    bwtf[1] = *(const short8*)&BwT[r * 72 + 32 + g * 8];

    size_t base = ((size_t)(b * 8 + h) * NCH + c) * 1024;
    {
        int p0t = w;
        short8 a0 = *(const short8*)&XhT[(p0t * 16 + r) * 72 + 0  + g * 8];
        short8 a1 = *(const short8*)&XhT[(p0t * 16 + r) * 72 + 32 + g * 8];
        f32x4 acc = (f32x4){0.f, 0.f, 0.f, 0.f};
        acc = __builtin_amdgcn_mfma_f32_16x16x32_bf16(a0, bwtf[0], acc, 0, 0, 0);
        acc = __builtin_amdgcn_mfma_f32_16x16x32_bf16(a1, bwtf[1], acc, 0, 0, 0);
        #pragma unroll
        for (int reg = 0; reg < 4; ++reg)
            sbuf[base + (size_t)(p0t * 16 + g * 4 + reg) * 16 + r] = acc[reg];
    }
}

// ---------------------------------------------------------------
// phase 2: sequential chain over chunks; 4-deep batched prefetch.
__global__ void __launch_bounds__(256) k_chain(const float* __restrict__ sbuf,
                                               const float* __restrict__ cdf,
                                               float* __restrict__ hin) {
    int h = blockIdx.x, b = blockIdx.y;
    int tid = threadIdx.x;
    float4 H = make_float4(0.f, 0.f, 0.f, 0.f);
    size_t base = (size_t)((b * 8 + h) * NCH) * 1024;
    const float* cdp = cdf + (size_t)(b * 8 + h) * NCH;
    for (int c0 = 0; c0 < NCH; c0 += 4) {
        float4 S[4];
        float cd[4];
        #pragma unroll
        for (int j = 0; j < 4; ++j) {
            S[j]  = *(const float4*)&sbuf[base + (size_t)(c0 + j) * 1024 + tid * 4];
            cd[j] = cdp[c0 + j];
        }
        #pragma unroll
        for (int j = 0; j < 4; ++j) {
            *(float4*)&hin[base + (size_t)(c0 + j) * 1024 + tid * 4] = H;
            H.x = cd[j] * H.x + S[j].x;
            H.y = cd[j] * H.y + S[j].y;
            H.z = cd[j] * H.z + S[j].z;
            H.w = cd[j] * H.w + S[j].w;
        }
    }
}

// ---------------------------------------------------------------
// SSD scan phase 3 via MFMA (4 waves/block; wave w owns i-tile i0t=w).
// z_bf holds PRE-SILU'd z. Pre-gate y staged bf16 in LDS; vectorized gate+store pass.
__global__ void __launch_bounds__(256) k_ssc2(const ushort_t* __restrict__ xbc,
                                              const ushort_t* __restrict__ z_bf,
                                              const float* __restrict__ brec,
                                              const float* __restrict__ Dp,
                                              const float* __restrict__ hin,
                                              ushort_t* __restrict__ yg_out) {
    __shared__ ushort_t XhT[64 * 72];
    __shared__ ushort_t Pl [64 * 72];   // recBC [64][40] -> P [i][j] -> Y [i][p]
    __shared__ float Sl[64], Tl[64], El[64];
    const int c = blockIdx.x, h = blockIdx.y, b = blockIdx.z;
    const int tid = threadIdx.x;
    const int w = tid >> 6, lane = tid & 63;
    const int g = lane >> 4, r = lane & 15;
    const size_t row0 = (size_t)b * L_SEQ + (size_t)c * QCH;
    const size_t bhc = (size_t)(b * 8 + h) * NCH + c;

    // stage B+C coalesced -> bf16 recBC (stride 40)
    #pragma unroll
    for (int it2 = 0; it2 < 2; ++it2) {
        int idx = it2 * 256 + tid;
        int row = idx >> 3, q = idx & 7;
        float4 v = *(const float4*)(brec + (row0 + row) * RECW + q * 4);
        uint_t u0 = (uint_t)f2b(v.x) | ((uint_t)f2b(v.y) << 16);
        uint_t u1 = (uint_t)f2b(v.z) | ((uint_t)f2b(v.w) << 16);
        *(uint2*)&Pl[row * 40 + q * 4] = make_uint2(u0, u1);
    }
    stage_xht(xbc, row0, h, tid, XhT);

    if (w == 0) {
        float ldA = brec[(row0 + lane) * RECW + 48 + h];
        float dtv = brec[(row0 + lane) * RECW + 40 + h];
        float S = ldA;
        #pragma unroll
        for (int d = 1; d < 64; d <<= 1) {
            float o = __shfl(S, (lane >= d) ? (lane - d) : 0);
            if (lane >= d) S += o;
        }
        Sl[lane] = S;
        Tl[lane] = S - __logf(dtv);
        El[lane] = __expf(S);
    }
    __syncthreads();

    // frags: all bwf, own cwf only (K padded 16->32, g>=2 zero)
    short8 cwf, bwf[4];
    #pragma unroll
    for (int t4 = 0; t4 < 4; ++t4) {
        if (g < 2) {
            bwf[t4] = *(const short8*)&Pl[(t4 * 16 + r) * 40 + 0 + g * 8];
        } else {
            #pragma unroll
            for (int e = 0; e < 8; ++e) bwf[t4][e] = 0;
        }
    }
    if (g < 2) {
        cwf = *(const short8*)&Pl[(w * 16 + r) * 40 + 16 + g * 8];
    } else {
        #pragma unroll
        for (int e = 0; e < 8; ++e) cwf[e] = 0;
    }
    __syncthreads();   // frags hoisted before Pl overwritten

    // ---- MFMA-1: wave w computes i-tile i0t=w -> P rows i=w*16+r
    {
        int i = w * 16 + r;
        float si = Sl[i];
        #pragma unroll
        for (int j0t = 0; j0t < 4; ++j0t) {
            f32x4 m = (f32x4){0.f, 0.f, 0.f, 0.f};
            m = __builtin_amdgcn_mfma_f32_16x16x32_bf16(bwf[j0t], cwf, m, 0, 0, 0);
            float4 tj = *(const float4*)&Tl[j0t * 16 + g * 4];
            ushort_t pv[4];
            #pragma unroll
            for (int reg = 0; reg < 4; ++reg) {
                int j = j0t * 16 + g * 4 + reg;
                float tjv = (reg == 0) ? tj.x : (reg == 1) ? tj.y : (reg == 2) ? tj.z : tj.w;
                float mask = (j <= i) ? __expf(si - tjv) : 0.f;
                pv[reg] = f2b(m[reg] * mask);
            }
            uint2 packed = make_uint2((uint_t)pv[0] | ((uint_t)pv[1] << 16),
                                      (uint_t)pv[2] | ((uint_t)pv[3] << 16));
            *(uint2*)&Pl[i * 72 + j0t * 16 + g * 4] = packed;
        }
    }
    __syncthreads();

    // hoist P-frags (own rows), Xh frags, Hin frags
    short8 pa0 = *(const short8*)&Pl[(w * 16 + r) * 72 + 0  + g * 8];
    short8 pa1 = *(const short8*)&Pl[(w * 16 + r) * 72 + 32 + g * 8];
    short8 xhf[4][2];
    #pragma unroll
    for (int p0t = 0; p0t < 4; ++p0t)
        #pragma unroll
        for (int kk = 0; kk < 2; ++kk)
            xhf[p0t][kk] = *(const short8*)&XhT[(p0t * 16 + r) * 72 + kk * 32 + g * 8];
    short8 hinf[4];
    #pragma unroll
    for (int p0t = 0; p0t < 4; ++p0t)
        hinf[p0t] = frag8(hin + bhc * 1024 + (size_t)(p0t * 16 + r) * 16 + g * 8, g < 2);

    const float Dh = Dp[h];
    float4 e4 = *(const float4*)&El[w * 16 + g * 4];
    __syncthreads();   // all P-frags hoisted before Pl is overwritten with Y

    // ---- compute y (pre-gate), write bf16 into Pl[i][p] (stride 72)
    #pragma unroll
    for (int p0t = 0; p0t < 4; ++p0t) {
        f32x4 acc = (f32x4){0.f, 0.f, 0.f, 0.f};
        acc = __builtin_amdgcn_mfma_f32_16x16x32_bf16(cwf, hinf[p0t], acc, 0, 0, 0);
        acc[0] *= e4.x; acc[1] *= e4.y; acc[2] *= e4.z; acc[3] *= e4.w;
        acc = __builtin_amdgcn_mfma_f32_16x16x32_bf16(pa0, xhf[p0t][0], acc, 0, 0, 0);
        acc = __builtin_amdgcn_mfma_f32_16x16x32_bf16(pa1, xhf[p0t][1], acc, 0, 0, 0);
        int p = p0t * 16 + r;
        #pragma unroll
        for (int reg = 0; reg < 4; ++reg) {
            int i = w * 16 + g * 4 + reg;
            float xhv = b2f(XhT[p * 72 + i]);
            Pl[i * 72 + p] = f2b(acc[reg] + Dh * xhv);
        }
    }
    __syncthreads();

    // ---- vectorized gate + store: 512 (row, 8-col-seg) items over 256 threads
    #pragma unroll
    for (int it6 = 0; it6 < 2; ++it6) {
        int t = it6 * 256 + tid;
        int i = t >> 3, seg = t & 7;
        size_t row = row0 + i;
        uint4 yv = *(const uint4*)&Pl[i * 72 + seg * 8];
        uint4 zv = *(const uint4*)(z_bf + row * 512 + h * 64 + seg * 8);
        uint4 ov;
        ov.x = gate2(yv.x, zv.x);
        ov.y = gate2(yv.y, zv.y);
        ov.z = gate2(yv.z, zv.z);
        ov.w = gate2(yv.w, zv.w);
        *(uint4*)(yg_out + row * 512 + h * 64 + seg * 8) = ov;
    }
}

// ---------------------------------------------------------------
__global__ void __launch_bounds__(256) k_scatter(const ushort_t* __restrict__ tmp,
                                                 const float* __restrict__ ub,
                                                 const float* __restrict__ xin,
                                                 float* __restrict__ out) {
    int tid = threadIdx.x;
    int w = tid & 127;
    int h = (blockIdx.x << 1) | (tid >> 7);
    int c = blockIdx.y >> 3, t = blockIdx.y & 7;
    int b = blockIdx.z;
    size_t row = (size_t)b * L_SEQ + t * 1024 + (h >> 2) * 32 + (w >> 2);
    int kk = c * 16 + (h & 3) * 4 + (w & 3);
    size_t oidx = (((size_t)(b * C_INCH + c) * T_N + t) << 14) + (size_t)h * W_IMG + w;
    out[oidx] = b2f(tmp[row * KPATCH + kk]) + ub[c] + xin[oidx];
}

// ---------------------------------------------------------------
extern "C" void kernel_launch(void* const* d_in, const int* in_sizes, int n_in,
                              void* d_out, int out_size, void* d_ws, size_t ws_size,
                              hipStream_t stream) {
    const float* x       = (const float*)d_in[0];
    const float* patch_w = (const float*)d_in[1];
    const float* patch_b = (const float*)d_in[2];
    const float* W_in    = (const float*)d_in[3];
    const float* conv_w  = (const float*)d_in[4];
    const float* conv_b  = (const float*)d_in[5];
    const float* dt_bias = (const float*)d_in[6];
    const float* A_log   = (const float*)d_in[7];
    const float* D_param = (const float*)d_in[8];
    const float* norm_w  = (const float*)d_in[9];
    const float* W_out   = (const float*)d_in[10];
    const float* unemb_w = (const float*)d_in[11];
    const float* unemb_b = (const float*)d_in[12];
    float* out = (float*)d_out;

    // ---- workspace carve ----
    char* p = (char*)d_ws;
    ushort_t* scratch = (ushort_t*)p; p += (size_t)BLROWS * 384 * 2;   // 25 MB (bf16 tmp)
    float* cdf  = (float*)p;   p += (size_t)32 * NCH * 4;
    float* sbuf = (float*)p;   p += (size_t)32 * NCH * 1024 * 4;       // 16.8 MB
    float* hin  = (float*)p;   p += (size_t)32 * NCH * 1024 * 4;       // 16.8 MB
    float* brec = (float*)p;   p += (size_t)BLROWS * RECW * 4;         // 7.3 MB
    ushort_t* Wt_p    = (ushort_t*)p; p += (size_t)256 * 384 * 2;
    ushort_t* Wt_in   = (ushort_t*)p; p += (size_t)1152 * 256 * 2;
    ushort_t* Wt_un   = (ushort_t*)p; p += (size_t)384 * 256 * 2;      // W_un^T bf16
    ushort_t* Wt_os   = (ushort_t*)p; p += (size_t)512 * 256 * 2;      // nw-scaled W_out bf16
    ushort_t* Wt_comb = (ushort_t*)p; p += (size_t)384 * 512 * 2;      // fused out-proj+unembed
    ushort_t* xs     = (ushort_t*)p; p += (size_t)BLROWS * DM_ * 2;    // 16.8 MB
    ushort_t* xbc    = (ushort_t*)p; p += (size_t)BLROWS * 512 * 2;    // 33.5 MB
    ushort_t* z_bf   = (ushort_t*)p; p += (size_t)BLROWS * 512 * 2;    // 33.5 MB (silu'd z)
    ushort_t* xbcdt  = (ushort_t*)p; p += (size_t)BLROWS * 640 * 2;    // 41.9 MB (later: yg)
    size_t need = (size_t)(p - (char*)d_ws);
    if (ws_size < need) return;

    ushort_t* tmp = scratch;            // bf16 fused-output [BL][368]
    ushort_t* yg  = xbcdt;              // yg overlays xbcdt (dead after conv)

    k_castpad<<<256, 384, 0, stream>>>(patch_w, Wt_p);
    k_transcast<<<1152, 256, 0, stream>>>(W_in, Wt_in, 256, 1064);
    k_transcast<<<384, 256, 0, stream>>>(unemb_w, Wt_un, 256, 368);   // A: W_un^T [384][256]
    k_scaleW<<<512, 256, 0, stream>>>(W_out, norm_w, Wt_os);          // B: nw-scaled W_out [512][256]
    // Wt_comb[n][mp] = sum_d Wt_un[n][d] * Wt_os[mp][d]  (tiny MFMA GEMM, 12 blocks)
    k_mgemm<256, 512, true, false, false><<<dim3(4, 3), 256, 0, stream>>>(Wt_un, 256, Wt_os, Wt_comb, 512, 0, nullptr);

    // fused im2col + patch GEMM
    k_pgemm<<<dim3(2, 256), 256, 0, stream>>>(x, Wt_p, xs, patch_b);

    // in-proj split: silu(z) cols 0..511 -> z_bf; xBC+dt cols 512..1063 -> xbcdt
    k_mgemm<256, 512, true, false, true><<<dim3(4, 256), 256, 0, stream>>>(xs, 256, Wt_in, z_bf, 512, 0, nullptr);
    k_mgemm<256, 552, true, false, false><<<dim3(5, 256), 256, 0, stream>>>(xs, 256, Wt_in + (size_t)512 * 256, xbcdt, 640, 0, nullptr);

    k_conv<<<BLROWS / 8, 256, 0, stream>>>(xbcdt, conv_w, conv_b, dt_bias, A_log, xbc, brec);

    k_scan1m<<<dim3(NCH, 8, 4), 256, 0, stream>>>(xbc, brec, sbuf, cdf);
    k_chain<<<dim3(8, 4), 256, 0, stream>>>(sbuf, cdf, hin);
    k_ssc2<<<dim3(NCH, 8, 4), 256, 0, stream>>>(xbc, z_bf, brec, D_param, hin, yg);

    // fused out-proj + RMSNorm + unembed: tmp[BL,368] = rms(yg) @ Wt_comb
    k_mgemm<512, 368, true, true, false><<<dim3(3, 256), 256, 0, stream>>>(yg, 512, Wt_comb, tmp, KPATCH, 0, nullptr);

    k_scatter<<<dim3(64, 184, 4), 256, 0, stream>>>(tmp, unemb_b, x, out);
}

// Round 19
// 266.814 us; speedup vs baseline: 1.0687x; 1.0105x over previous
//
#include <hip/hip_runtime.h>
#include <hip/hip_bf16.h>
#include <cstdint>
#include <cstddef>

// ---- problem constants ----
#define B_N       4
#define C_INCH    23
#define T_N       8
#define W_IMG     128
#define L_SEQ     8192
#define BLROWS    32768      // B_N * L_SEQ
#define DM_       256
#define D_INNER_  512
#define CONV_DIM_ 544
#define D_PROJ    1064
#define KPATCH    368        // C_INCH*4*4
#define QCH       64         // scan chunk length
#define NCH       128        // chunks per batch
#define RECW      56         // packed scan record (floats): B16 C16 dA8 dt8 ldA8

typedef unsigned short ushort_t;
typedef unsigned int uint_t;
typedef __attribute__((ext_vector_type(8))) short short8;
typedef __attribute__((ext_vector_type(4))) float f32x4;

__device__ __forceinline__ float b2f(ushort_t u) {
    union { float f; uint_t u; } v; v.u = ((uint_t)u) << 16; return v.f;
}
__device__ __forceinline__ ushort_t f2b(float f) {
    union { float f; uint_t u; } v; v.f = f;
    uint_t r = v.u + 0x7fffu + ((v.u >> 16) & 1u);
    return (ushort_t)(r >> 16);
}

// async global->LDS, 16B per lane. LDS dest = wave-uniform base + lane*16.
__device__ __forceinline__ void gload_lds16(const ushort_t* g, ushort_t* l) {
    __builtin_amdgcn_global_load_lds(
        (const __attribute__((address_space(1))) unsigned int*)g,
        (__attribute__((address_space(3))) unsigned int*)l, 16, 0, 0);
}

// build a bf16 short8 frag from 8 consecutive f32 (or zeros if !live)
__device__ __forceinline__ short8 frag8(const float* q, bool live) {
    short8 f;
    if (live) {
        float4 lo = *(const float4*)q, hi = *(const float4*)(q + 4);
        f[0] = (short)f2b(lo.x); f[1] = (short)f2b(lo.y);
        f[2] = (short)f2b(lo.z); f[3] = (short)f2b(lo.w);
        f[4] = (short)f2b(hi.x); f[5] = (short)f2b(hi.y);
        f[6] = (short)f2b(hi.z); f[7] = (short)f2b(hi.w);
    } else {
        #pragma unroll
        for (int e = 0; e < 8; ++e) f[e] = 0;
    }
    return f;
}

// gate one packed pair: out = pack(bf16(y0*z0), bf16(y1*z1))
__device__ __forceinline__ uint_t gate2(uint_t yw, uint_t zw) {
    float y0 = b2f((ushort_t)(yw & 0xffffu)), y1 = b2f((ushort_t)(yw >> 16));
    float z0 = b2f((ushort_t)(zw & 0xffffu)), z1 = b2f((ushort_t)(zw >> 16));
    return (uint_t)f2b(y0 * z0) | ((uint_t)f2b(y1 * z1) << 16);
}

// ---------------------------------------------------------------
// weight prep: dst[Npad][K] bf16 = transpose(src[K][N] fp32) * (rscale?rscale[k]:1)
__global__ void k_transcast(const float* __restrict__ src, ushort_t* __restrict__ dst,
                            int K, int N, const float* __restrict__ rscale) {
    int n = blockIdx.x;
    for (int k = threadIdx.x; k < K; k += 256) {
        float v = 0.f;
        if (n < N) {
            v = src[(size_t)k * N + n];
            if (rscale) v *= rscale[k];
        }
        dst[(size_t)n * K + k] = f2b(v);
    }
}

// patch weights are already [d][k]: direct cast + pad k to 384
__global__ void k_castpad(const float* __restrict__ src, ushort_t* __restrict__ dst) {
    int d = blockIdx.x; int k = threadIdx.x;   // 384 threads
    dst[d * 384 + k] = (k < KPATCH) ? f2b(src[d * KPATCH + k]) : (ushort_t)0;
}

// ---------------------------------------------------------------
// fused patch-embed GEMM: xs[BL,256] = gather-im2col(x)[BL,384] @ Wt_p[256][384] + pb.
__global__ void __launch_bounds__(256) k_pgemm(const float* __restrict__ x,
                                               const ushort_t* __restrict__ Wt,
                                               ushort_t* __restrict__ Cv,
                                               const float* __restrict__ bias) {
    __shared__ ushort_t Al[128 * 64];
    __shared__ ushort_t Bl[128 * 64];
    const int tid = threadIdx.x;
    const int w = tid >> 6, lane = tid & 63;
    const int wr = w >> 1, wc = w & 1;
    const int rowbase = blockIdx.y * 128;
    const int colbase = blockIdx.x * 128;
    const int g = lane >> 4, r = lane & 15;
    const int b  = rowbase >> 13;
    const int t  = (rowbase >> 10) & 7;
    const int hp0 = (rowbase >> 5) & 31;

    f32x4 acc[4][4];
    #pragma unroll
    for (int i = 0; i < 4; ++i)
        #pragma unroll
        for (int j = 0; j < 4; ++j) acc[i][j] = (f32x4){0.f, 0.f, 0.f, 0.f};

    for (int it = 0; it < 6; ++it) {        // K=384, BK=64
        int k0 = it * 64;
        __syncthreads();
        #pragma unroll
        for (int i2 = 0; i2 < 4; ++i2) {
            int s = i2 * 256 + (w << 6) + lane;
            int row = s >> 3;
            int c16 = (s & 7) ^ (row & 7);
            gload_lds16(Wt + (size_t)(colbase + row) * 384 + k0 + c16 * 8,
                        &Bl[(size_t)(i2 * 256 + (w << 6)) * 8]);
        }
        #pragma unroll
        for (int i2 = 0; i2 < 8; ++i2) {
            int idx = i2 * 256 + tid;
            int row = idx >> 4, kq = idx & 15;
            int c = (k0 >> 4) + (kq >> 2);
            int i = kq & 3;
            uint_t u0 = 0, u1 = 0;
            if (c < C_INCH) {
                int hp = hp0 + (row >> 5), wp = row & 31;
                const float4 v = *(const float4*)&x[(((size_t)(b * C_INCH + c) * T_N + t) << 14)
                                                    + (size_t)(hp * 4 + i) * W_IMG + wp * 4];
                u0 = (uint_t)f2b(v.x) | ((uint_t)f2b(v.y) << 16);
                u1 = (uint_t)f2b(v.z) | ((uint_t)f2b(v.w) << 16);
            }
            int slot = (row << 3) + ((kq >> 1) ^ (row & 7));
            *(uint2*)&Al[(size_t)slot * 8 + (kq & 1) * 4] = make_uint2(u0, u1);
        }
        __syncthreads();

        short8 af[2][4], bf[2][4];
        #pragma unroll
        for (int ks = 0; ks < 2; ++ks)
            #pragma unroll
            for (int mi = 0; mi < 4; ++mi) {
                int row = (wr << 6) + (mi << 4) + r;
                int c16 = ((ks << 2) | g) ^ (row & 7);
                af[ks][mi] = *(const short8*)&Al[(size_t)((row << 3) + c16) * 8];
            }
        #pragma unroll
        for (int ks = 0; ks < 2; ++ks)
            #pragma unroll
            for (int ni = 0; ni < 4; ++ni) {
                int row = (wc << 6) + (ni << 4) + r;
                int c16 = ((ks << 2) | g) ^ (row & 7);
                bf[ks][ni] = *(const short8*)&Bl[(size_t)((row << 3) + c16) * 8];
            }
        #pragma unroll
        for (int ks = 0; ks < 2; ++ks)
            #pragma unroll
            for (int mi = 0; mi < 4; ++mi)
                #pragma unroll
                for (int ni = 0; ni < 4; ++ni)
                    acc[mi][ni] = __builtin_amdgcn_mfma_f32_16x16x32_bf16(
                        af[ks][mi], bf[ks][ni], acc[mi][ni], 0, 0, 0);
    }

    #pragma unroll
    for (int mi = 0; mi < 4; ++mi) {
        int rw = rowbase + (wr << 6) + (mi << 4) + (g << 2);
        #pragma unroll
        for (int ni = 0; ni < 4; ++ni) {
            int col = colbase + (wc << 6) + (ni << 4) + r;
            float bv = bias[col];
            f32x4 v = acc[mi][ni];
            #pragma unroll
            for (int j = 0; j < 4; ++j)
                Cv[(size_t)(rw + j) * DM_ + col] = f2b(v[j] + bv);
        }
    }
}

// ---------------------------------------------------------------
// MFMA GEMM; ASCALE = fused RMSNorm row-scale; SILU = silu() on outputs.
template <int K, int N, bool CBF, bool ASCALE, bool SILU>
__global__ void __launch_bounds__(256) k_mgemm(const ushort_t* __restrict__ A, const int lda,
                                               const ushort_t* __restrict__ Wt,
                                               void* __restrict__ Cv, const int ldc, const int coff,
                                               const float* __restrict__ bias) {
    __shared__ ushort_t Al[128 * 64];
    __shared__ ushort_t Bl[128 * 64];
    const int tid = threadIdx.x;
    const int w = tid >> 6, lane = tid & 63;
    const int wr = w >> 1, wc = w & 1;
    const int rowbase = blockIdx.y * 128;
    const int colbase = blockIdx.x * 128;
    const int g = lane >> 4, r = lane & 15;

    f32x4 acc[4][4];
    #pragma unroll
    for (int i = 0; i < 4; ++i)
        #pragma unroll
        for (int j = 0; j < 4; ++j) acc[i][j] = (f32x4){0.f, 0.f, 0.f, 0.f};
    float rs[4] = {0.f, 0.f, 0.f, 0.f};

    for (int k0 = 0; k0 < K; k0 += 64) {
        __syncthreads();
        #pragma unroll
        for (int it = 0; it < 4; ++it) {
            int s = it * 256 + (w << 6) + lane;
            int row = s >> 3;
            int c16 = (s & 7) ^ (row & 7);
            gload_lds16(A + (size_t)(rowbase + row) * lda + k0 + c16 * 8,
                        &Al[(size_t)(it * 256 + (w << 6)) * 8]);
        }
        #pragma unroll
        for (int it = 0; it < 4; ++it) {
            int s = it * 256 + (w << 6) + lane;
            int row = s >> 3;
            int c16 = (s & 7) ^ (row & 7);
            gload_lds16(Wt + (size_t)(colbase + row) * K + k0 + c16 * 8,
                        &Bl[(size_t)(it * 256 + (w << 6)) * 8]);
        }
        __syncthreads();

        short8 af[2][4], bf[2][4];
        #pragma unroll
        for (int ks = 0; ks < 2; ++ks)
            #pragma unroll
            for (int mi = 0; mi < 4; ++mi) {
                int row = (wr << 6) + (mi << 4) + r;
                int c16 = ((ks << 2) | g) ^ (row & 7);
                af[ks][mi] = *(const short8*)&Al[(size_t)((row << 3) + c16) * 8];
            }
        #pragma unroll
        for (int ks = 0; ks < 2; ++ks)
            #pragma unroll
            for (int ni = 0; ni < 4; ++ni) {
                int row = (wc << 6) + (ni << 4) + r;
                int c16 = ((ks << 2) | g) ^ (row & 7);
                bf[ks][ni] = *(const short8*)&Bl[(size_t)((row << 3) + c16) * 8];
            }
        if (ASCALE) {
            #pragma unroll
            for (int ks = 0; ks < 2; ++ks)
                #pragma unroll
                for (int mi = 0; mi < 4; ++mi)
                    #pragma unroll
                    for (int e = 0; e < 8; ++e) {
                        float v = b2f((ushort_t)af[ks][mi][e]);
                        rs[mi] += v * v;
                    }
        }
        #pragma unroll
        for (int ks = 0; ks < 2; ++ks)
            #pragma unroll
            for (int mi = 0; mi < 4; ++mi)
                #pragma unroll
                for (int ni = 0; ni < 4; ++ni)
                    acc[mi][ni] = __builtin_amdgcn_mfma_f32_16x16x32_bf16(
                        af[ks][mi], bf[ks][ni], acc[mi][ni], 0, 0, 0);
    }

    #pragma unroll
    for (int mi = 0; mi < 4; ++mi) {
        int rw = rowbase + (wr << 6) + (mi << 4) + (g << 2);
        float sj[4] = {1.f, 1.f, 1.f, 1.f};
        if (ASCALE) {
            float s = rs[mi];
            s += __shfl_xor(s, 16);
            s += __shfl_xor(s, 32);
            float sc = rsqrtf(s * (1.f / 512.f) + 1e-5f);
            #pragma unroll
            for (int j = 0; j < 4; ++j) sj[j] = __shfl(sc, 4 * g + j);
        }
        #pragma unroll
        for (int ni = 0; ni < 4; ++ni) {
            int col = colbase + (wc << 6) + (ni << 4) + r;
            if (col < N) {
                float bv = bias ? bias[col] : 0.f;
                f32x4 v = acc[mi][ni];
                #pragma unroll
                for (int j = 0; j < 4; ++j) {
                    size_t cidx = (size_t)(rw + j) * ldc + coff + col;
                    float vr = v[j] * sj[j] + bv;
                    if (SILU) vr = vr / (1.f + __expf(-vr));
                    if (CBF) ((ushort_t*)Cv)[cidx] = f2b(vr);
                    else     ((float*)Cv)[cidx]   = vr;
                }
            }
        }
    }
}

// ---------------------------------------------------------------
// causal depthwise conv + silu; brec: B[0..15] C[16..31] dA[32..39] dt[40..47] ldA[48..55]
__global__ void __launch_bounds__(256) k_conv(const ushort_t* __restrict__ xbcdt,
                                              const float* __restrict__ cw,
                                              const float* __restrict__ cb,
                                              const float* __restrict__ dtb,
                                              const float* __restrict__ alog,
                                              ushort_t* __restrict__ xbc,
                                              float* __restrict__ brec) {
    int tid = threadIdx.x;
    int rb = blockIdx.x * 8;
    int srb = rb & (L_SEQ - 1);
    #pragma unroll
    for (int it = 0; it < 3; ++it) {
        int ch = it * 256 + tid;
        if (ch >= 552) break;
        if (ch < CONV_DIM_) {
            float w0 = cw[ch * 4 + 0], w1 = cw[ch * 4 + 1];
            float w2 = cw[ch * 4 + 2], w3 = cw[ch * 4 + 3];
            float bias = cb[ch];
            float win[11];
            #pragma unroll
            for (int j = 0; j < 11; ++j) {
                int sj = srb + j - 3;
                win[j] = (sj >= 0) ? b2f(xbcdt[(size_t)(rb + j - 3) * 640 + ch]) : 0.f;
            }
            #pragma unroll
            for (int r = 0; r < 8; ++r) {
                float acc = bias + win[r] * w0 + win[r + 1] * w1 + win[r + 2] * w2 + win[r + 3] * w3;
                float s = acc / (1.f + __expf(-acc));
                size_t row = rb + r;
                if (ch < 512) xbc[row * 512 + ch] = f2b(s);
                else          brec[row * RECW + (ch - 512)] = s;
            }
        } else {
            int h = ch - CONV_DIM_;
            float A = -__expf(alog[h]);
            float db = dtb[h];
            #pragma unroll
            for (int r = 0; r < 8; ++r) {
                size_t row = rb + r;
                float v = b2f(xbcdt[row * 640 + ch]) + db;
                float sp = (v > 20.f) ? v : log1pf(__expf(v));
                brec[row * RECW + 32 + h] = __expf(sp * A);   // dA
                brec[row * RECW + 40 + h] = sp;               // dt
                brec[row * RECW + 48 + h] = sp * A;           // ldA (log decay)
            }
        }
    }
}

// ---------------------------------------------------------------
// stage XhT[p][j] for one chunk using all 256 threads.
__device__ __forceinline__ void stage_xht(const ushort_t* __restrict__ xbc,
                                          size_t row0, int h, int tid,
                                          ushort_t* __restrict__ XhT) {
    int j = tid & 63, q4 = tid >> 6;
    const uint4* xsrc = (const uint4*)(xbc + (row0 + j) * 512 + h * 64);
    uint4 xa = xsrc[q4 * 2], xb = xsrc[q4 * 2 + 1];
    #pragma unroll
    for (int pp = 0; pp < 16; ++pp) {
        int p = q4 * 16 + pp;
        uint4 v = (pp < 8) ? xa : xb;
        int sub = (pp >> 1) & 3;
        uint_t word = (sub == 0) ? v.x : (sub == 1) ? v.y : (sub == 2) ? v.z : v.w;
        XhT[p * 72 + j] = (ushort_t)((pp & 1) ? (word >> 16) : (word & 0xffffu));
    }
}

// ---------------------------------------------------------------
// scan phase 1 via MFMA (4 waves/block; wave w owns p-tile p0t=w).
__global__ void __launch_bounds__(256) k_scan1m(const ushort_t* __restrict__ xbc,
                                                const float* __restrict__ brec,
                                                float* __restrict__ sbuf,
                                                float* __restrict__ cdf) {
    __shared__ ushort_t XhT[64 * 72];
    __shared__ float    Bst[64 * 20];
    __shared__ ushort_t BwT[16 * 72];
    const int c = blockIdx.x, h = blockIdx.y, b = blockIdx.z;
    const int tid = threadIdx.x;
    const int w = tid >> 6, lane = tid & 63;
    const int g = lane >> 4, r = lane & 15;
    const size_t row0 = (size_t)b * L_SEQ + (size_t)c * QCH;

    {
        int row = tid >> 2, q = tid & 3;
        float4 v = *(const float4*)(brec + (row0 + row) * RECW + q * 4);
        *(float4*)&Bst[row * 20 + q * 4] = v;
    }
    stage_xht(xbc, row0, h, tid, XhT);

    if (w == 0) {
        float ldA = brec[(row0 + lane) * RECW + 48 + h];
        float dtv = brec[(row0 + lane) * RECW + 40 + h];
        float S = ldA;
        #pragma unroll
        for (int d = 1; d < 64; d <<= 1) {
            float o = __shfl(S, (lane >= d) ? (lane - d) : 0);
            if (lane >= d) S += o;
        }
        float Stot = __shfl(S, 63);
        float wj = dtv * __expf(Stot - S);
        __builtin_amdgcn_s_barrier();
        const float* bp = &Bst[lane * 20];
        float4 b0 = *(const float4*)bp;
        float4 b1 = *(const float4*)(bp + 4);
        float4 b2 = *(const float4*)(bp + 8);
        float4 b3 = *(const float4*)(bp + 12);
        float bv[16] = {b0.x,b0.y,b0.z,b0.w, b1.x,b1.y,b1.z,b1.w,
                        b2.x,b2.y,b2.z,b2.w, b3.x,b3.y,b3.z,b3.w};
        #pragma unroll
        for (int n = 0; n < 16; ++n)
            BwT[n * 72 + lane] = f2b(bv[n] * wj);
        if (lane == 63) cdf[(b * 8 + h) * NCH + c] = __expf(S);
    } else {
        __builtin_amdgcn_s_barrier();
    }
    __syncthreads();

    short8 bwtf[2];
    bwtf[0] = *(const short8*)&BwT[r * 72 + 0  + g * 8];
    bwtf[1] = *(const short8*)&BwT[r * 72 + 32 + g * 8];

    size_t base = ((size_t)(b * 8 + h) * NCH + c) * 1024;
    {
        int p0t = w;
        short8 a0 = *(const short8*)&XhT[(p0t * 16 + r) * 72 + 0  + g * 8];
        short8 a1 = *(const short8*)&XhT[(p0t * 16 + r) * 72 + 32 + g * 8];
        f32x4 acc = (f32x4){0.f, 0.f, 0.f, 0.f};
        acc = __builtin_amdgcn_mfma_f32_16x16x32_bf16(a0, bwtf[0], acc, 0, 0, 0);
        acc = __builtin_amdgcn_mfma_f32_16x16x32_bf16(a1, bwtf[1], acc, 0, 0, 0);
        #pragma unroll
        for (int reg = 0; reg < 4; ++reg)
            sbuf[base + (size_t)(p0t * 16 + g * 4 + reg) * 16 + r] = acc[reg];
    }
}

// ---------------------------------------------------------------
// phase 2: sequential chain over chunks; 4-deep batched prefetch.
__global__ void __launch_bounds__(256) k_chain(const float* __restrict__ sbuf,
                                               const float* __restrict__ cdf,
                                               float* __restrict__ hin) {
    int h = blockIdx.x, b = blockIdx.y;
    int tid = threadIdx.x;
    float4 H = make_float4(0.f, 0.f, 0.f, 0.f);
    size_t base = (size_t)((b * 8 + h) * NCH) * 1024;
    const float* cdp = cdf + (size_t)(b * 8 + h) * NCH;
    for (int c0 = 0; c0 < NCH; c0 += 4) {
        float4 S[4];
        float cd[4];
        #pragma unroll
        for (int j = 0; j < 4; ++j) {
            S[j]  = *(const float4*)&sbuf[base + (size_t)(c0 + j) * 1024 + tid * 4];
            cd[j] = cdp[c0 + j];
        }
        #pragma unroll
        for (int j = 0; j < 4; ++j) {
            *(float4*)&hin[base + (size_t)(c0 + j) * 1024 + tid * 4] = H;
            H.x = cd[j] * H.x + S[j].x;
            H.y = cd[j] * H.y + S[j].y;
            H.z = cd[j] * H.z + S[j].z;
            H.w = cd[j] * H.w + S[j].w;
        }
    }
}

// ---------------------------------------------------------------
// SSD scan phase 3 via MFMA (4 waves/block; wave w owns i-tile i0t=w).
// z_bf holds PRE-SILU'd z. Pre-gate y staged bf16 in LDS; vectorized gate+store pass.
__global__ void __launch_bounds__(256) k_ssc2(const ushort_t* __restrict__ xbc,
                                              const ushort_t* __restrict__ z_bf,
                                              const float* __restrict__ brec,
                                              const float* __restrict__ Dp,
                                              const float* __restrict__ hin,
                                              ushort_t* __restrict__ yg_out) {
    __shared__ ushort_t XhT[64 * 72];
    __shared__ ushort_t Pl [64 * 72];   // recBC [64][40] -> P [i][j] -> Y [i][p]
    __shared__ float Sl[64], Tl[64], El[64];
    const int c = blockIdx.x, h = blockIdx.y, b = blockIdx.z;
    const int tid = threadIdx.x;
    const int w = tid >> 6, lane = tid & 63;
    const int g = lane >> 4, r = lane & 15;
    const size_t row0 = (size_t)b * L_SEQ + (size_t)c * QCH;
    const size_t bhc = (size_t)(b * 8 + h) * NCH + c;

    // stage B+C coalesced -> bf16 recBC (stride 40)
    #pragma unroll
    for (int it2 = 0; it2 < 2; ++it2) {
        int idx = it2 * 256 + tid;
        int row = idx >> 3, q = idx & 7;
        float4 v = *(const float4*)(brec + (row0 + row) * RECW + q * 4);
        uint_t u0 = (uint_t)f2b(v.x) | ((uint_t)f2b(v.y) << 16);
        uint_t u1 = (uint_t)f2b(v.z) | ((uint_t)f2b(v.w) << 16);
        *(uint2*)&Pl[row * 40 + q * 4] = make_uint2(u0, u1);
    }
    stage_xht(xbc, row0, h, tid, XhT);

    if (w == 0) {
        float ldA = brec[(row0 + lane) * RECW + 48 + h];
        float dtv = brec[(row0 + lane) * RECW + 40 + h];
        float S = ldA;
        #pragma unroll
        for (int d = 1; d < 64; d <<= 1) {
            float o = __shfl(S, (lane >= d) ? (lane - d) : 0);
            if (lane >= d) S += o;
        }
        Sl[lane] = S;
        Tl[lane] = S - __logf(dtv);
        El[lane] = __expf(S);
    }
    __syncthreads();

    // frags: all bwf, own cwf only (K padded 16->32, g>=2 zero)
    short8 cwf, bwf[4];
    #pragma unroll
    for (int t4 = 0; t4 < 4; ++t4) {
        if (g < 2) {
            bwf[t4] = *(const short8*)&Pl[(t4 * 16 + r) * 40 + 0 + g * 8];
        } else {
            #pragma unroll
            for (int e = 0; e < 8; ++e) bwf[t4][e] = 0;
        }
    }
    if (g < 2) {
        cwf = *(const short8*)&Pl[(w * 16 + r) * 40 + 16 + g * 8];
    } else {
        #pragma unroll
        for (int e = 0; e < 8; ++e) cwf[e] = 0;
    }
    __syncthreads();   // frags hoisted before Pl overwritten

    // ---- MFMA-1: wave w computes i-tile i0t=w -> P rows i=w*16+r
    {
        int i = w * 16 + r;
        float si = Sl[i];
        #pragma unroll
        for (int j0t = 0; j0t < 4; ++j0t) {
            f32x4 m = (f32x4){0.f, 0.f, 0.f, 0.f};
            m = __builtin_amdgcn_mfma_f32_16x16x32_bf16(bwf[j0t], cwf, m, 0, 0, 0);
            float4 tj = *(const float4*)&Tl[j0t * 16 + g * 4];
            ushort_t pv[4];
            #pragma unroll
            for (int reg = 0; reg < 4; ++reg) {
                int j = j0t * 16 + g * 4 + reg;
                float tjv = (reg == 0) ? tj.x : (reg == 1) ? tj.y : (reg == 2) ? tj.z : tj.w;
                float mask = (j <= i) ? __expf(si - tjv) : 0.f;
                pv[reg] = f2b(m[reg] * mask);
            }
            uint2 packed = make_uint2((uint_t)pv[0] | ((uint_t)pv[1] << 16),
                                      (uint_t)pv[2] | ((uint_t)pv[3] << 16));
            *(uint2*)&Pl[i * 72 + j0t * 16 + g * 4] = packed;
        }
    }
    __syncthreads();

    // hoist P-frags (own rows), Xh frags, Hin frags
    short8 pa0 = *(const short8*)&Pl[(w * 16 + r) * 72 + 0  + g * 8];
    short8 pa1 = *(const short8*)&Pl[(w * 16 + r) * 72 + 32 + g * 8];
    short8 xhf[4][2];
    #pragma unroll
    for (int p0t = 0; p0t < 4; ++p0t)
        #pragma unroll
        for (int kk = 0; kk < 2; ++kk)
            xhf[p0t][kk] = *(const short8*)&XhT[(p0t * 16 + r) * 72 + kk * 32 + g * 8];
    short8 hinf[4];
    #pragma unroll
    for (int p0t = 0; p0t < 4; ++p0t)
        hinf[p0t] = frag8(hin + bhc * 1024 + (size_t)(p0t * 16 + r) * 16 + g * 8, g < 2);

    const float Dh = Dp[h];
    float4 e4 = *(const float4*)&El[w * 16 + g * 4];
    __syncthreads();   // all P-frags hoisted before Pl is overwritten with Y

    // ---- compute y (pre-gate), write bf16 into Pl[i][p] (stride 72)
    #pragma unroll
    for (int p0t = 0; p0t < 4; ++p0t) {
        f32x4 acc = (f32x4){0.f, 0.f, 0.f, 0.f};
        acc = __builtin_amdgcn_mfma_f32_16x16x32_bf16(cwf, hinf[p0t], acc, 0, 0, 0);
        acc[0] *= e4.x; acc[1] *= e4.y; acc[2] *= e4.z; acc[3] *= e4.w;
        acc = __builtin_amdgcn_mfma_f32_16x16x32_bf16(pa0, xhf[p0t][0], acc, 0, 0, 0);
        acc = __builtin_amdgcn_mfma_f32_16x16x32_bf16(pa1, xhf[p0t][1], acc, 0, 0, 0);
        int p = p0t * 16 + r;
        #pragma unroll
        for (int reg = 0; reg < 4; ++reg) {
            int i = w * 16 + g * 4 + reg;
            float xhv = b2f(XhT[p * 72 + i]);
            Pl[i * 72 + p] = f2b(acc[reg] + Dh * xhv);
        }
    }
    __syncthreads();

    // ---- vectorized gate + store: 512 (row, 8-col-seg) items over 256 threads
    #pragma unroll
    for (int it6 = 0; it6 < 2; ++it6) {
        int t = it6 * 256 + tid;
        int i = t >> 3, seg = t & 7;
        size_t row = row0 + i;
        uint4 yv = *(const uint4*)&Pl[i * 72 + seg * 8];
        uint4 zv = *(const uint4*)(z_bf + row * 512 + h * 64 + seg * 8);
        uint4 ov;
        ov.x = gate2(yv.x, zv.x);
        ov.y = gate2(yv.y, zv.y);
        ov.z = gate2(yv.z, zv.z);
        ov.w = gate2(yv.w, zv.w);
        *(uint4*)(yg_out + row * 512 + h * 64 + seg * 8) = ov;
    }
}

// ---------------------------------------------------------------
__global__ void __launch_bounds__(256) k_scatter(const ushort_t* __restrict__ tmp,
                                                 const float* __restrict__ ub,
                                                 const float* __restrict__ xin,
                                                 float* __restrict__ out) {
    int tid = threadIdx.x;
    int w = tid & 127;
    int h = (blockIdx.x << 1) | (tid >> 7);
    int c = blockIdx.y >> 3, t = blockIdx.y & 7;
    int b = blockIdx.z;
    size_t row = (size_t)b * L_SEQ + t * 1024 + (h >> 2) * 32 + (w >> 2);
    int kk = c * 16 + (h & 3) * 4 + (w & 3);
    size_t oidx = (((size_t)(b * C_INCH + c) * T_N + t) << 14) + (size_t)h * W_IMG + w;
    out[oidx] = b2f(tmp[row * KPATCH + kk]) + ub[c] + xin[oidx];
}

// ---------------------------------------------------------------
extern "C" void kernel_launch(void* const* d_in, const int* in_sizes, int n_in,
                              void* d_out, int out_size, void* d_ws, size_t ws_size,
                              hipStream_t stream) {
    const float* x       = (const float*)d_in[0];
    const float* patch_w = (const float*)d_in[1];
    const float* patch_b = (const float*)d_in[2];
    const float* W_in    = (const float*)d_in[3];
    const float* conv_w  = (const float*)d_in[4];
    const float* conv_b  = (const float*)d_in[5];
    const float* dt_bias = (const float*)d_in[6];
    const float* A_log   = (const float*)d_in[7];
    const float* D_param = (const float*)d_in[8];
    const float* norm_w  = (const float*)d_in[9];
    const float* W_out   = (const float*)d_in[10];
    const float* unemb_w = (const float*)d_in[11];
    const float* unemb_b = (const float*)d_in[12];
    float* out = (float*)d_out;

    // ---- workspace carve ----
    char* p = (char*)d_ws;
    ushort_t* scratch = (ushort_t*)p; p += (size_t)BLROWS * 384 * 2;   // 25 MB (bf16 tmp)
    float* cdf  = (float*)p;   p += (size_t)32 * NCH * 4;
    float* sbuf = (float*)p;   p += (size_t)32 * NCH * 1024 * 4;       // 16.8 MB
    float* hin  = (float*)p;   p += (size_t)32 * NCH * 1024 * 4;       // 16.8 MB
    float* brec = (float*)p;   p += (size_t)BLROWS * RECW * 4;         // 7.3 MB
    ushort_t* Wt_p   = (ushort_t*)p; p += (size_t)256 * 384 * 2;
    ushort_t* Wt_in  = (ushort_t*)p; p += (size_t)1152 * 256 * 2;
    ushort_t* Wt_out = (ushort_t*)p; p += (size_t)256 * 512 * 2;
    ushort_t* Wt_un  = (ushort_t*)p; p += (size_t)384 * 256 * 2;
    ushort_t* xs     = (ushort_t*)p; p += (size_t)BLROWS * DM_ * 2;    // 16.8 MB
    ushort_t* xbc    = (ushort_t*)p; p += (size_t)BLROWS * 512 * 2;    // 33.5 MB
    ushort_t* z_bf   = (ushort_t*)p; p += (size_t)BLROWS * 512 * 2;    // 33.5 MB (silu'd z)
    ushort_t* xbcdt  = (ushort_t*)p; p += (size_t)BLROWS * 640 * 2;    // 41.9 MB (later: yg)
    size_t need = (size_t)(p - (char*)d_ws);
    if (ws_size < need) return;

    ushort_t* tmp = scratch;            // bf16 unembed output [BL][368]
    ushort_t* yg  = xbcdt;              // yg overlays xbcdt (dead after conv)

    k_castpad<<<256, 384, 0, stream>>>(patch_w, Wt_p);
    k_transcast<<<1152, 256, 0, stream>>>(W_in, Wt_in, 256, 1064, nullptr);
    k_transcast<<<256, 256, 0, stream>>>(W_out, Wt_out, 512, 256, norm_w);  // fold RMSNorm weight
    k_transcast<<<384, 256, 0, stream>>>(unemb_w, Wt_un, 256, 368, nullptr);

    // fused im2col + patch GEMM
    k_pgemm<<<dim3(2, 256), 256, 0, stream>>>(x, Wt_p, xs, patch_b);

    // in-proj split: silu(z) cols 0..511 -> z_bf; xBC+dt cols 512..1063 -> xbcdt
    k_mgemm<256, 512, true, false, true><<<dim3(4, 256), 256, 0, stream>>>(xs, 256, Wt_in, z_bf, 512, 0, nullptr);
    k_mgemm<256, 552, true, false, false><<<dim3(5, 256), 256, 0, stream>>>(xs, 256, Wt_in + (size_t)512 * 256, xbcdt, 640, 0, nullptr);

    k_conv<<<BLROWS / 8, 256, 0, stream>>>(xbcdt, conv_w, conv_b, dt_bias, A_log, xbc, brec);

    k_scan1m<<<dim3(NCH, 8, 4), 256, 0, stream>>>(xbc, brec, sbuf, cdf);
    k_chain<<<dim3(8, 4), 256, 0, stream>>>(sbuf, cdf, hin);
    k_ssc2<<<dim3(NCH, 8, 4), 256, 0, stream>>>(xbc, z_bf, brec, D_param, hin, yg);

    // out-proj with in-kernel fused RMSNorm (ASCALE): out_seq bf16 -> xs
    k_mgemm<512, 256, true, true, false><<<dim3(2, 256), 256, 0, stream>>>(yg, 512, Wt_out, xs, DM_, 0, nullptr);

    // unembed: tmp[BL,368] = out_seq @ W_un  (xs L2-resident -> cheap re-reads)
    k_mgemm<256, 368, true, false, false><<<dim3(3, 256), 256, 0, stream>>>(xs, 256, Wt_un, tmp, KPATCH, 0, nullptr);

    k_scatter<<<dim3(64, 184, 4), 256, 0, stream>>>(tmp, unemb_b, x, out);
}

// Round 20
// 241.113 us; speedup vs baseline: 1.1826x; 1.1066x over previous
//
#include <hip/hip_runtime.h>
#include <hip/hip_bf16.h>
#include <cstdint>
#include <cstddef>

// ---- problem constants ----
#define B_N       4
#define C_INCH    23
#define T_N       8
#define W_IMG     128
#define L_SEQ     8192
#define BLROWS    32768      // B_N * L_SEQ
#define DM_       256
#define D_INNER_  512
#define CONV_DIM_ 544
#define D_PROJ    1064
#define KPATCH    368        // C_INCH*4*4
#define QCH       64         // scan chunk length
#define NCH       128        // chunks per batch
#define RECW      56         // packed scan record (floats): B16 C16 dA8 dt8 ldA8

typedef unsigned short ushort_t;
typedef unsigned int uint_t;
typedef __attribute__((ext_vector_type(8))) short short8;
typedef __attribute__((ext_vector_type(4))) float f32x4;

__device__ __forceinline__ float b2f(ushort_t u) {
    union { float f; uint_t u; } v; v.u = ((uint_t)u) << 16; return v.f;
}
__device__ __forceinline__ ushort_t f2b(float f) {
    union { float f; uint_t u; } v; v.f = f;
    uint_t r = v.u + 0x7fffu + ((v.u >> 16) & 1u);
    return (ushort_t)(r >> 16);
}

// async global->LDS, 16B per lane. LDS dest = wave-uniform base + lane*16.
__device__ __forceinline__ void gload_lds16(const ushort_t* g, ushort_t* l) {
    __builtin_amdgcn_global_load_lds(
        (const __attribute__((address_space(1))) unsigned int*)g,
        (__attribute__((address_space(3))) unsigned int*)l, 16, 0, 0);
}

// build a bf16 short8 frag from 8 consecutive f32 (or zeros if !live)
__device__ __forceinline__ short8 frag8(const float* q, bool live) {
    short8 f;
    if (live) {
        float4 lo = *(const float4*)q, hi = *(const float4*)(q + 4);
        f[0] = (short)f2b(lo.x); f[1] = (short)f2b(lo.y);
        f[2] = (short)f2b(lo.z); f[3] = (short)f2b(lo.w);
        f[4] = (short)f2b(hi.x); f[5] = (short)f2b(hi.y);
        f[6] = (short)f2b(hi.z); f[7] = (short)f2b(hi.w);
    } else {
        #pragma unroll
        for (int e = 0; e < 8; ++e) f[e] = 0;
    }
    return f;
}

// gate one packed pair: out = pack(bf16(y0*z0), bf16(y1*z1))
__device__ __forceinline__ uint_t gate2(uint_t yw, uint_t zw) {
    float y0 = b2f((ushort_t)(yw & 0xffffu)), y1 = b2f((ushort_t)(yw >> 16));
    float z0 = b2f((ushort_t)(zw & 0xffffu)), z1 = b2f((ushort_t)(zw >> 16));
    return (uint_t)f2b(y0 * z0) | ((uint_t)f2b(y1 * z1) << 16);
}

// ---------------------------------------------------------------
// weight prep: dst[Npad][K] bf16 = transpose(src[K][N] fp32) * (rscale?rscale[k]:1)
__global__ void k_transcast(const float* __restrict__ src, ushort_t* __restrict__ dst,
                            int K, int N, const float* __restrict__ rscale) {
    int n = blockIdx.x;
    for (int k = threadIdx.x; k < K; k += 256) {
        float v = 0.f;
        if (n < N) {
            v = src[(size_t)k * N + n];
            if (rscale) v *= rscale[k];
        }
        dst[(size_t)n * K + k] = f2b(v);
    }
}

// patch weights are already [d][k]: direct cast + pad k to 384
__global__ void k_castpad(const float* __restrict__ src, ushort_t* __restrict__ dst) {
    int d = blockIdx.x; int k = threadIdx.x;   // 384 threads
    dst[d * 384 + k] = (k < KPATCH) ? f2b(src[d * KPATCH + k]) : (ushort_t)0;
}

// ---------------------------------------------------------------
// fused patch-embed GEMM: xs[BL,256] = gather-im2col(x)[BL,384] @ Wt_p[256][384] + pb.
__global__ void __launch_bounds__(256) k_pgemm(const float* __restrict__ x,
                                               const ushort_t* __restrict__ Wt,
                                               ushort_t* __restrict__ Cv,
                                               const float* __restrict__ bias) {
    __shared__ ushort_t Al[128 * 64];
    __shared__ ushort_t Bl[128 * 64];
    const int tid = threadIdx.x;
    const int w = tid >> 6, lane = tid & 63;
    const int wr = w >> 1, wc = w & 1;
    const int rowbase = blockIdx.y * 128;
    const int colbase = blockIdx.x * 128;
    const int g = lane >> 4, r = lane & 15;
    const int b  = rowbase >> 13;
    const int t  = (rowbase >> 10) & 7;
    const int hp0 = (rowbase >> 5) & 31;

    f32x4 acc[4][4];
    #pragma unroll
    for (int i = 0; i < 4; ++i)
        #pragma unroll
        for (int j = 0; j < 4; ++j) acc[i][j] = (f32x4){0.f, 0.f, 0.f, 0.f};

    for (int it = 0; it < 6; ++it) {        // K=384, BK=64
        int k0 = it * 64;
        __syncthreads();
        #pragma unroll
        for (int i2 = 0; i2 < 4; ++i2) {
            int s = i2 * 256 + (w << 6) + lane;
            int row = s >> 3;
            int c16 = (s & 7) ^ (row & 7);
            gload_lds16(Wt + (size_t)(colbase + row) * 384 + k0 + c16 * 8,
                        &Bl[(size_t)(i2 * 256 + (w << 6)) * 8]);
        }
        #pragma unroll
        for (int i2 = 0; i2 < 8; ++i2) {
            int idx = i2 * 256 + tid;
            int row = idx >> 4, kq = idx & 15;
            int c = (k0 >> 4) + (kq >> 2);
            int i = kq & 3;
            uint_t u0 = 0, u1 = 0;
            if (c < C_INCH) {
                int hp = hp0 + (row >> 5), wp = row & 31;
                const float4 v = *(const float4*)&x[(((size_t)(b * C_INCH + c) * T_N + t) << 14)
                                                    + (size_t)(hp * 4 + i) * W_IMG + wp * 4];
                u0 = (uint_t)f2b(v.x) | ((uint_t)f2b(v.y) << 16);
                u1 = (uint_t)f2b(v.z) | ((uint_t)f2b(v.w) << 16);
            }
            int slot = (row << 3) + ((kq >> 1) ^ (row & 7));
            *(uint2*)&Al[(size_t)slot * 8 + (kq & 1) * 4] = make_uint2(u0, u1);
        }
        __syncthreads();

        short8 af[2][4], bf[2][4];
        #pragma unroll
        for (int ks = 0; ks < 2; ++ks)
            #pragma unroll
            for (int mi = 0; mi < 4; ++mi) {
                int row = (wr << 6) + (mi << 4) + r;
                int c16 = ((ks << 2) | g) ^ (row & 7);
                af[ks][mi] = *(const short8*)&Al[(size_t)((row << 3) + c16) * 8];
            }
        #pragma unroll
        for (int ks = 0; ks < 2; ++ks)
            #pragma unroll
            for (int ni = 0; ni < 4; ++ni) {
                int row = (wc << 6) + (ni << 4) + r;
                int c16 = ((ks << 2) | g) ^ (row & 7);
                bf[ks][ni] = *(const short8*)&Bl[(size_t)((row << 3) + c16) * 8];
            }
        #pragma unroll
        for (int ks = 0; ks < 2; ++ks)
            #pragma unroll
            for (int mi = 0; mi < 4; ++mi)
                #pragma unroll
                for (int ni = 0; ni < 4; ++ni)
                    acc[mi][ni] = __builtin_amdgcn_mfma_f32_16x16x32_bf16(
                        af[ks][mi], bf[ks][ni], acc[mi][ni], 0, 0, 0);
    }

    #pragma unroll
    for (int mi = 0; mi < 4; ++mi) {
        int rw = rowbase + (wr << 6) + (mi << 4) + (g << 2);
        #pragma unroll
        for (int ni = 0; ni < 4; ++ni) {
            int col = colbase + (wc << 6) + (ni << 4) + r;
            float bv = bias[col];
            f32x4 v = acc[mi][ni];
            #pragma unroll
            for (int j = 0; j < 4; ++j)
                Cv[(size_t)(rw + j) * DM_ + col] = f2b(v[j] + bv);
        }
    }
}

// ---------------------------------------------------------------
// MFMA GEMM; ASCALE = fused RMSNorm row-scale; SILU = silu() on outputs.
template <int K, int N, bool CBF, bool ASCALE, bool SILU>
__global__ void __launch_bounds__(256) k_mgemm(const ushort_t* __restrict__ A, const int lda,
                                               const ushort_t* __restrict__ Wt,
                                               void* __restrict__ Cv, const int ldc, const int coff,
                                               const float* __restrict__ bias) {
    __shared__ ushort_t Al[128 * 64];
    __shared__ ushort_t Bl[128 * 64];
    const int tid = threadIdx.x;
    const int w = tid >> 6, lane = tid & 63;
    const int wr = w >> 1, wc = w & 1;
    const int rowbase = blockIdx.y * 128;
    const int colbase = blockIdx.x * 128;
    const int g = lane >> 4, r = lane & 15;

    f32x4 acc[4][4];
    #pragma unroll
    for (int i = 0; i < 4; ++i)
        #pragma unroll
        for (int j = 0; j < 4; ++j) acc[i][j] = (f32x4){0.f, 0.f, 0.f, 0.f};
    float rs[4] = {0.f, 0.f, 0.f, 0.f};

    for (int k0 = 0; k0 < K; k0 += 64) {
        __syncthreads();
        #pragma unroll
        for (int it = 0; it < 4; ++it) {
            int s = it * 256 + (w << 6) + lane;
            int row = s >> 3;
            int c16 = (s & 7) ^ (row & 7);
            gload_lds16(A + (size_t)(rowbase + row) * lda + k0 + c16 * 8,
                        &Al[(size_t)(it * 256 + (w << 6)) * 8]);
        }
        #pragma unroll
        for (int it = 0; it < 4; ++it) {
            int s = it * 256 + (w << 6) + lane;
            int row = s >> 3;
            int c16 = (s & 7) ^ (row & 7);
            gload_lds16(Wt + (size_t)(colbase + row) * K + k0 + c16 * 8,
                        &Bl[(size_t)(it * 256 + (w << 6)) * 8]);
        }
        __syncthreads();

        short8 af[2][4], bf[2][4];
        #pragma unroll
        for (int ks = 0; ks < 2; ++ks)
            #pragma unroll
            for (int mi = 0; mi < 4; ++mi) {
                int row = (wr << 6) + (mi << 4) + r;
                int c16 = ((ks << 2) | g) ^ (row & 7);
                af[ks][mi] = *(const short8*)&Al[(size_t)((row << 3) + c16) * 8];
            }
        #pragma unroll
        for (int ks = 0; ks < 2; ++ks)
            #pragma unroll
            for (int ni = 0; ni < 4; ++ni) {
                int row = (wc << 6) + (ni << 4) + r;
                int c16 = ((ks << 2) | g) ^ (row & 7);
                bf[ks][ni] = *(const short8*)&Bl[(size_t)((row << 3) + c16) * 8];
            }
        if (ASCALE) {
            #pragma unroll
            for (int ks = 0; ks < 2; ++ks)
                #pragma unroll
                for (int mi = 0; mi < 4; ++mi)
                    #pragma unroll
                    for (int e = 0; e < 8; ++e) {
                        float v = b2f((ushort_t)af[ks][mi][e]);
                        rs[mi] += v * v;
                    }
        }
        #pragma unroll
        for (int ks = 0; ks < 2; ++ks)
            #pragma unroll
            for (int mi = 0; mi < 4; ++mi)
                #pragma unroll
                for (int ni = 0; ni < 4; ++ni)
                    acc[mi][ni] = __builtin_amdgcn_mfma_f32_16x16x32_bf16(
                        af[ks][mi], bf[ks][ni], acc[mi][ni], 0, 0, 0);
    }

    #pragma unroll
    for (int mi = 0; mi < 4; ++mi) {
        int rw = rowbase + (wr << 6) + (mi << 4) + (g << 2);
        float sj[4] = {1.f, 1.f, 1.f, 1.f};
        if (ASCALE) {
            float s = rs[mi];
            s += __shfl_xor(s, 16);
            s += __shfl_xor(s, 32);
            float sc = rsqrtf(s * (1.f / 512.f) + 1e-5f);
            #pragma unroll
            for (int j = 0; j < 4; ++j) sj[j] = __shfl(sc, 4 * g + j);
        }
        #pragma unroll
        for (int ni = 0; ni < 4; ++ni) {
            int col = colbase + (wc << 6) + (ni << 4) + r;
            if (col < N) {
                float bv = bias ? bias[col] : 0.f;
                f32x4 v = acc[mi][ni];
                #pragma unroll
                for (int j = 0; j < 4; ++j) {
                    size_t cidx = (size_t)(rw + j) * ldc + coff + col;
                    float vr = v[j] * sj[j] + bv;
                    if (SILU) vr = vr / (1.f + __expf(-vr));
                    if (CBF) ((ushort_t*)Cv)[cidx] = f2b(vr);
                    else     ((float*)Cv)[cidx]   = vr;
                }
            }
        }
    }
}

// ---------------------------------------------------------------
// causal depthwise conv + silu; brec: B[0..15] C[16..31] dA[32..39] dt[40..47] ldA[48..55]
__global__ void __launch_bounds__(256) k_conv(const ushort_t* __restrict__ xbcdt,
                                              const float* __restrict__ cw,
                                              const float* __restrict__ cb,
                                              const float* __restrict__ dtb,
                                              const float* __restrict__ alog,
                                              ushort_t* __restrict__ xbc,
                                              float* __restrict__ brec) {
    int tid = threadIdx.x;
    int rb = blockIdx.x * 8;
    int srb = rb & (L_SEQ - 1);
    #pragma unroll
    for (int it = 0; it < 3; ++it) {
        int ch = it * 256 + tid;
        if (ch >= 552) break;
        if (ch < CONV_DIM_) {
            float w0 = cw[ch * 4 + 0], w1 = cw[ch * 4 + 1];
            float w2 = cw[ch * 4 + 2], w3 = cw[ch * 4 + 3];
            float bias = cb[ch];
            float win[11];
            #pragma unroll
            for (int j = 0; j < 11; ++j) {
                int sj = srb + j - 3;
                win[j] = (sj >= 0) ? b2f(xbcdt[(size_t)(rb + j - 3) * 640 + ch]) : 0.f;
            }
            #pragma unroll
            for (int r = 0; r < 8; ++r) {
                float acc = bias + win[r] * w0 + win[r + 1] * w1 + win[r + 2] * w2 + win[r + 3] * w3;
                float s = acc / (1.f + __expf(-acc));
                size_t row = rb + r;
                if (ch < 512) xbc[row * 512 + ch] = f2b(s);
                else          brec[row * RECW + (ch - 512)] = s;
            }
        } else {
            int h = ch - CONV_DIM_;
            float A = -__expf(alog[h]);
            float db = dtb[h];
            #pragma unroll
            for (int r = 0; r < 8; ++r) {
                size_t row = rb + r;
                float v = b2f(xbcdt[row * 640 + ch]) + db;
                float sp = (v > 20.f) ? v : log1pf(__expf(v));
                brec[row * RECW + 32 + h] = __expf(sp * A);   // dA
                brec[row * RECW + 40 + h] = sp;               // dt
                brec[row * RECW + 48 + h] = sp * A;           // ldA (log decay)
            }
        }
    }
}

// ---------------------------------------------------------------
// stage XhT[p][j] for one chunk using all 256 threads.
__device__ __forceinline__ void stage_xht(const ushort_t* __restrict__ xbc,
                                          size_t row0, int h, int tid,
                                          ushort_t* __restrict__ XhT) {
    int j = tid & 63, q4 = tid >> 6;
    const uint4* xsrc = (const uint4*)(xbc + (row0 + j) * 512 + h * 64);
    uint4 xa = xsrc[q4 * 2], xb = xsrc[q4 * 2 + 1];
    #pragma unroll
    for (int pp = 0; pp < 16; ++pp) {
        int p = q4 * 16 + pp;
        uint4 v = (pp < 8) ? xa : xb;
        int sub = (pp >> 1) & 3;
        uint_t word = (sub == 0) ? v.x : (sub == 1) ? v.y : (sub == 2) ? v.z : v.w;
        XhT[p * 72 + j] = (ushort_t)((pp & 1) ? (word >> 16) : (word & 0xffffu));
    }
}

// ---------------------------------------------------------------
// scan phase 1 via MFMA (4 waves/block; wave w owns p-tile p0t=w).
__global__ void __launch_bounds__(256) k_scan1m(const ushort_t* __restrict__ xbc,
                                                const float* __restrict__ brec,
                                                float* __restrict__ sbuf,
                                                float* __restrict__ cdf) {
    __shared__ ushort_t XhT[64 * 72];
    __shared__ float    Bst[64 * 20];
    __shared__ ushort_t BwT[16 * 72];
    const int c = blockIdx.x, h = blockIdx.y, b = blockIdx.z;
    const int tid = threadIdx.x;
    const int w = tid >> 6, lane = tid & 63;
    const int g = lane >> 4, r = lane & 15;
    const size_t row0 = (size_t)b * L_SEQ + (size_t)c * QCH;

    {
        int row = tid >> 2, q = tid & 3;
        float4 v = *(const float4*)(brec + (row0 + row) * RECW + q * 4);
        *(float4*)&Bst[row * 20 + q * 4] = v;
    }
    stage_xht(xbc, row0, h, tid, XhT);

    if (w == 0) {
        float ldA = brec[(row0 + lane) * RECW + 48 + h];
        float dtv = brec[(row0 + lane) * RECW + 40 + h];
        float S = ldA;
        #pragma unroll
        for (int d = 1; d < 64; d <<= 1) {
            float o = __shfl(S, (lane >= d) ? (lane - d) : 0);
            if (lane >= d) S += o;
        }
        float Stot = __shfl(S, 63);
        float wj = dtv * __expf(Stot - S);
        __builtin_amdgcn_s_barrier();
        const float* bp = &Bst[lane * 20];
        float4 b0 = *(const float4*)bp;
        float4 b1 = *(const float4*)(bp + 4);
        float4 b2 = *(const float4*)(bp + 8);
        float4 b3 = *(const float4*)(bp + 12);
        float bv[16] = {b0.x,b0.y,b0.z,b0.w, b1.x,b1.y,b1.z,b1.w,
                        b2.x,b2.y,b2.z,b2.w, b3.x,b3.y,b3.z,b3.w};
        #pragma unroll
        for (int n = 0; n < 16; ++n)
            BwT[n * 72 + lane] = f2b(bv[n] * wj);
        if (lane == 63) cdf[(b * 8 + h) * NCH + c] = __expf(S);
    } else {
        __builtin_amdgcn_s_barrier();
    }
    __syncthreads();

    short8 bwtf[2];
    bwtf[0] = *(const short8*)&BwT[r * 72 + 0  + g * 8];
    bwtf[1] = *(const short8*)&BwT[r * 72 + 32 + g * 8];

    size_t base = ((size_t)(b * 8 + h) * NCH + c) * 1024;
    {
        int p0t = w;
        short8 a0 = *(const short8*)&XhT[(p0t * 16 + r) * 72 + 0  + g * 8];
        short8 a1 = *(const short8*)&XhT[(p0t * 16 + r) * 72 + 32 + g * 8];
        f32x4 acc = (f32x4){0.f, 0.f, 0.f, 0.f};
        acc = __builtin_amdgcn_mfma_f32_16x16x32_bf16(a0, bwtf[0], acc, 0, 0, 0);
        acc = __builtin_amdgcn_mfma_f32_16x16x32_bf16(a1, bwtf[1], acc, 0, 0, 0);
        #pragma unroll
        for (int reg = 0; reg < 4; ++reg)
            sbuf[base + (size_t)(p0t * 16 + g * 4 + reg) * 16 + r] = acc[reg];
    }
}

// ---------------------------------------------------------------
// phase 2: sequential chain over chunks (tiny).
__global__ void __launch_bounds__(256) k_chain(const float* __restrict__ sbuf,
                                               const float* __restrict__ cdf,
                                               float* __restrict__ hin) {
    int h = blockIdx.x, b = blockIdx.y;
    int tid = threadIdx.x;
    float4 H = make_float4(0.f, 0.f, 0.f, 0.f);
    size_t base = (size_t)((b * 8 + h) * NCH) * 1024;
    for (int c = 0; c < NCH; ++c) {
        *(float4*)&hin[base + (size_t)c * 1024 + tid * 4] = H;
        float cdfv = cdf[(b * 8 + h) * NCH + c];
        float4 S = *(const float4*)&sbuf[base + (size_t)c * 1024 + tid * 4];
        H.x = cdfv * H.x + S.x;
        H.y = cdfv * H.y + S.y;
        H.z = cdfv * H.z + S.z;
        H.w = cdfv * H.w + S.w;
    }
}

// ---------------------------------------------------------------
// SSD scan phase 3 via MFMA (4 waves/block; wave w owns i-tile i0t=w).
// z_bf holds PRE-SILU'd z. Pre-gate y staged bf16 in LDS; vectorized gate+store pass.
__global__ void __launch_bounds__(256) k_ssc2(const ushort_t* __restrict__ xbc,
                                              const ushort_t* __restrict__ z_bf,
                                              const float* __restrict__ brec,
                                              const float* __restrict__ Dp,
                                              const float* __restrict__ hin,
                                              ushort_t* __restrict__ yg_out) {
    __shared__ ushort_t XhT[64 * 72];
    __shared__ ushort_t Pl [64 * 72];   // recBC [64][40] -> P [i][j] -> Y [i][p]
    __shared__ float Sl[64], Tl[64], El[64];
    const int c = blockIdx.x, h = blockIdx.y, b = blockIdx.z;
    const int tid = threadIdx.x;
    const int w = tid >> 6, lane = tid & 63;
    const int g = lane >> 4, r = lane & 15;
    const size_t row0 = (size_t)b * L_SEQ + (size_t)c * QCH;
    const size_t bhc = (size_t)(b * 8 + h) * NCH + c;

    // stage B+C coalesced -> bf16 recBC (stride 40)
    #pragma unroll
    for (int it2 = 0; it2 < 2; ++it2) {
        int idx = it2 * 256 + tid;
        int row = idx >> 3, q = idx & 7;
        float4 v = *(const float4*)(brec + (row0 + row) * RECW + q * 4);
        uint_t u0 = (uint_t)f2b(v.x) | ((uint_t)f2b(v.y) << 16);
        uint_t u1 = (uint_t)f2b(v.z) | ((uint_t)f2b(v.w) << 16);
        *(uint2*)&Pl[row * 40 + q * 4] = make_uint2(u0, u1);
    }
    stage_xht(xbc, row0, h, tid, XhT);

    if (w == 0) {
        float ldA = brec[(row0 + lane) * RECW + 48 + h];
        float dtv = brec[(row0 + lane) * RECW + 40 + h];
        float S = ldA;
        #pragma unroll
        for (int d = 1; d < 64; d <<= 1) {
            float o = __shfl(S, (lane >= d) ? (lane - d) : 0);
            if (lane >= d) S += o;
        }
        Sl[lane] = S;
        Tl[lane] = S - __logf(dtv);
        El[lane] = __expf(S);
    }
    __syncthreads();

    // frags: all bwf, own cwf only (K padded 16->32, g>=2 zero)
    short8 cwf, bwf[4];
    #pragma unroll
    for (int t4 = 0; t4 < 4; ++t4) {
        if (g < 2) {
            bwf[t4] = *(const short8*)&Pl[(t4 * 16 + r) * 40 + 0 + g * 8];
        } else {
            #pragma unroll
            for (int e = 0; e < 8; ++e) bwf[t4][e] = 0;
        }
    }
    if (g < 2) {
        cwf = *(const short8*)&Pl[(w * 16 + r) * 40 + 16 + g * 8];
    } else {
        #pragma unroll
        for (int e = 0; e < 8; ++e) cwf[e] = 0;
    }
    __syncthreads();   // frags hoisted before Pl overwritten

    // ---- MFMA-1: wave w computes i-tile i0t=w -> P rows i=w*16+r
    {
        int i = w * 16 + r;
        float si = Sl[i];
        #pragma unroll
        for (int j0t = 0; j0t < 4; ++j0t) {
            f32x4 m = (f32x4){0.f, 0.f, 0.f, 0.f};
            m = __builtin_amdgcn_mfma_f32_16x16x32_bf16(bwf[j0t], cwf, m, 0, 0, 0);
            float4 tj = *(const float4*)&Tl[j0t * 16 + g * 4];
            ushort_t pv[4];
            #pragma unroll
            for (int reg = 0; reg < 4; ++reg) {
                int j = j0t * 16 + g * 4 + reg;
                float tjv = (reg == 0) ? tj.x : (reg == 1) ? tj.y : (reg == 2) ? tj.z : tj.w;
                float mask = (j <= i) ? __expf(si - tjv) : 0.f;
                pv[reg] = f2b(m[reg] * mask);
            }
            uint2 packed = make_uint2((uint_t)pv[0] | ((uint_t)pv[1] << 16),
                                      (uint_t)pv[2] | ((uint_t)pv[3] << 16));
            *(uint2*)&Pl[i * 72 + j0t * 16 + g * 4] = packed;
        }
    }
    __syncthreads();

    // hoist P-frags (own rows), Xh frags, Hin frags
    short8 pa0 = *(const short8*)&Pl[(w * 16 + r) * 72 + 0  + g * 8];
    short8 pa1 = *(const short8*)&Pl[(w * 16 + r) * 72 + 32 + g * 8];
    short8 xhf[4][2];
    #pragma unroll
    for (int p0t = 0; p0t < 4; ++p0t)
        #pragma unroll
        for (int kk = 0; kk < 2; ++kk)
            xhf[p0t][kk] = *(const short8*)&XhT[(p0t * 16 + r) * 72 + kk * 32 + g * 8];
    short8 hinf[4];
    #pragma unroll
    for (int p0t = 0; p0t < 4; ++p0t)
        hinf[p0t] = frag8(hin + bhc * 1024 + (size_t)(p0t * 16 + r) * 16 + g * 8, g < 2);

    const float Dh = Dp[h];
    float4 e4 = *(const float4*)&El[w * 16 + g * 4];
    __syncthreads();   // all P-frags hoisted before Pl is overwritten with Y

    // ---- compute y (pre-gate), write bf16 into Pl[i][p] (stride 72)
    #pragma unroll
    for (int p0t = 0; p0t < 4; ++p0t) {
        f32x4 acc = (f32x4){0.f, 0.f, 0.f, 0.f};
        acc = __builtin_amdgcn_mfma_f32_16x16x32_bf16(cwf, hinf[p0t], acc, 0, 0, 0);
        acc[0] *= e4.x; acc[1] *= e4.y; acc[2] *= e4.z; acc[3] *= e4.w;
        acc = __builtin_amdgcn_mfma_f32_16x16x32_bf16(pa0, xhf[p0t][0], acc, 0, 0, 0);
        acc = __builtin_amdgcn_mfma_f32_16x16x32_bf16(pa1, xhf[p0t][1], acc, 0, 0, 0);
        int p = p0t * 16 + r;
        #pragma unroll
        for (int reg = 0; reg < 4; ++reg) {
            int i = w * 16 + g * 4 + reg;
            float xhv = b2f(XhT[p * 72 + i]);
            Pl[i * 72 + p] = f2b(acc[reg] + Dh * xhv);
        }
    }
    __syncthreads();

    // ---- vectorized gate + store: 512 (row, 8-col-seg) items over 256 threads
    #pragma unroll
    for (int it6 = 0; it6 < 2; ++it6) {
        int t = it6 * 256 + tid;
        int i = t >> 3, seg = t & 7;
        size_t row = row0 + i;
        uint4 yv = *(const uint4*)&Pl[i * 72 + seg * 8];
        uint4 zv = *(const uint4*)(z_bf + row * 512 + h * 64 + seg * 8);
        uint4 ov;
        ov.x = gate2(yv.x, zv.x);
        ov.y = gate2(yv.y, zv.y);
        ov.z = gate2(yv.z, zv.z);
        ov.w = gate2(yv.w, zv.w);
        *(uint4*)(yg_out + row * 512 + h * 64 + seg * 8) = ov;
    }
}

// ---------------------------------------------------------------
__global__ void __launch_bounds__(256) k_scatter(const ushort_t* __restrict__ tmp,
                                                 const float* __restrict__ ub,
                                                 const float* __restrict__ xin,
                                                 float* __restrict__ out) {
    int tid = threadIdx.x;
    int w = tid & 127;
    int h = (blockIdx.x << 1) | (tid >> 7);
    int c = blockIdx.y >> 3, t = blockIdx.y & 7;
    int b = blockIdx.z;
    size_t row = (size_t)b * L_SEQ + t * 1024 + (h >> 2) * 32 + (w >> 2);
    int kk = c * 16 + (h & 3) * 4 + (w & 3);
    size_t oidx = (((size_t)(b * C_INCH + c) * T_N + t) << 14) + (size_t)h * W_IMG + w;
    out[oidx] = b2f(tmp[row * KPATCH + kk]) + ub[c] + xin[oidx];
}

// ---------------------------------------------------------------
extern "C" void kernel_launch(void* const* d_in, const int* in_sizes, int n_in,
                              void* d_out, int out_size, void* d_ws, size_t ws_size,
                              hipStream_t stream) {
    const float* x       = (const float*)d_in[0];
    const float* patch_w = (const float*)d_in[1];
    const float* patch_b = (const float*)d_in[2];
    const float* W_in    = (const float*)d_in[3];
    const float* conv_w  = (const float*)d_in[4];
    const float* conv_b  = (const float*)d_in[5];
    const float* dt_bias = (const float*)d_in[6];
    const float* A_log   = (const float*)d_in[7];
    const float* D_param = (const float*)d_in[8];
    const float* norm_w  = (const float*)d_in[9];
    const float* W_out   = (const float*)d_in[10];
    const float* unemb_w = (const float*)d_in[11];
    const float* unemb_b = (const float*)d_in[12];
    float* out = (float*)d_out;

    // ---- workspace carve ----
    char* p = (char*)d_ws;
    ushort_t* scratch = (ushort_t*)p; p += (size_t)BLROWS * 384 * 2;   // 25 MB (bf16 tmp)
    float* cdf  = (float*)p;   p += (size_t)32 * NCH * 4;
    float* sbuf = (float*)p;   p += (size_t)32 * NCH * 1024 * 4;       // 16.8 MB
    float* hin  = (float*)p;   p += (size_t)32 * NCH * 1024 * 4;       // 16.8 MB
    float* brec = (float*)p;   p += (size_t)BLROWS * RECW * 4;         // 7.3 MB
    ushort_t* Wt_p   = (ushort_t*)p; p += (size_t)256 * 384 * 2;
    ushort_t* Wt_in  = (ushort_t*)p; p += (size_t)1152 * 256 * 2;
    ushort_t* Wt_out = (ushort_t*)p; p += (size_t)256 * 512 * 2;
    ushort_t* Wt_un  = (ushort_t*)p; p += (size_t)384 * 256 * 2;
    ushort_t* xs     = (ushort_t*)p; p += (size_t)BLROWS * DM_ * 2;    // 16.8 MB
    ushort_t* xbc    = (ushort_t*)p; p += (size_t)BLROWS * 512 * 2;    // 33.5 MB
    ushort_t* z_bf   = (ushort_t*)p; p += (size_t)BLROWS * 512 * 2;    // 33.5 MB (silu'd z)
    ushort_t* xbcdt  = (ushort_t*)p; p += (size_t)BLROWS * 640 * 2;    // 41.9 MB (later: yg)
    size_t need = (size_t)(p - (char*)d_ws);
    if (ws_size < need) return;

    ushort_t* tmp = scratch;            // bf16 unembed output [BL][368]
    ushort_t* yg  = xbcdt;              // yg overlays xbcdt (dead after conv)

    k_castpad<<<256, 384, 0, stream>>>(patch_w, Wt_p);
    k_transcast<<<1152, 256, 0, stream>>>(W_in, Wt_in, 256, 1064, nullptr);
    k_transcast<<<256, 256, 0, stream>>>(W_out, Wt_out, 512, 256, norm_w);  // fold RMSNorm weight
    k_transcast<<<384, 256, 0, stream>>>(unemb_w, Wt_un, 256, 368, nullptr);

    // fused im2col + patch GEMM
    k_pgemm<<<dim3(2, 256), 256, 0, stream>>>(x, Wt_p, xs, patch_b);

    // in-proj split: silu(z) cols 0..511 -> z_bf; xBC+dt cols 512..1063 -> xbcdt
    k_mgemm<256, 512, true, false, true><<<dim3(4, 256), 256, 0, stream>>>(xs, 256, Wt_in, z_bf, 512, 0, nullptr);
    k_mgemm<256, 552, true, false, false><<<dim3(5, 256), 256, 0, stream>>>(xs, 256, Wt_in + (size_t)512 * 256, xbcdt, 640, 0, nullptr);

    k_conv<<<BLROWS / 8, 256, 0, stream>>>(xbcdt, conv_w, conv_b, dt_bias, A_log, xbc, brec);

    k_scan1m<<<dim3(NCH, 8, 4), 256, 0, stream>>>(xbc, brec, sbuf, cdf);
    k_chain<<<dim3(8, 4), 256, 0, stream>>>(sbuf, cdf, hin);
    k_ssc2<<<dim3(NCH, 8, 4), 256, 0, stream>>>(xbc, z_bf, brec, D_param, hin, yg);

    // out-proj with in-kernel fused RMSNorm (ASCALE): out_seq bf16 -> xs
    k_mgemm<512, 256, true, true, false><<<dim3(2, 256), 256, 0, stream>>>(yg, 512, Wt_out, xs, DM_, 0, nullptr);

    // unembed: tmp[BL,368] = out_seq @ W_un  (xs L2-resident -> cheap re-reads)
    k_mgemm<256, 368, true, false, false><<<dim3(3, 256), 256, 0, stream>>>(xs, 256, Wt_un, tmp, KPATCH, 0, nullptr);

    k_scatter<<<dim3(64, 184, 4), 256, 0, stream>>>(tmp, unemb_b, x, out);
}